// Round 1
// baseline (1351.088 us; speedup 1.0000x reference)
//
#include <hip/hip_runtime.h>
#include <cmath>

#define NH 4

// ---------------- init / CSR build ----------------

__global__ void __launch_bounds__(64) init_affine_kernel(float* bnA, float* bnB) {
    int t = threadIdx.x;
    bnA[t] = 1.f;
    bnB[t] = 0.f;
}

__global__ void __launch_bounds__(256) hist_kernel(const int* __restrict__ dst,
                                                   int* __restrict__ deg, int E) {
    int e = blockIdx.x * 256 + threadIdx.x;
    if (e < E) atomicAdd(&deg[dst[e]], 1);
}

__global__ void __launch_bounds__(256) cntg_kernel(const int* __restrict__ gid,
                                                   int* __restrict__ cntg, int N) {
    int n = blockIdx.x * 256 + threadIdx.x;
    if (n < N) atomicAdd(&cntg[gid[n]], 1);
}

__global__ void __launch_bounds__(1024) scan_kernel(const int* __restrict__ deg,
                                                    int* __restrict__ row_ptr, int N) {
    __shared__ int s[1024];
    __shared__ int carry;
    int tid = threadIdx.x;
    if (tid == 0) carry = 0;
    __syncthreads();
    for (int base = 0; base < N; base += 1024) {
        int i = base + tid;
        int x = (i < N) ? deg[i] : 0;
        s[tid] = x;
        __syncthreads();
        for (int off = 1; off < 1024; off <<= 1) {
            int tv = (tid >= off) ? s[tid - off] : 0;
            __syncthreads();
            s[tid] += tv;
            __syncthreads();
        }
        int incl = s[tid];
        int c = carry;
        if (i < N) row_ptr[i] = c + incl - x;   // exclusive
        __syncthreads();
        if (tid == 1023) carry = c + s[1023];
        __syncthreads();
    }
    if (tid == 0) row_ptr[N] = carry;
}

__global__ void __launch_bounds__(256) scatter_kernel(const int* __restrict__ src,
                                                      const int* __restrict__ dst,
                                                      const int* __restrict__ row_ptr,
                                                      int* __restrict__ cursor,
                                                      int* __restrict__ col_src, int E) {
    int e = blockIdx.x * 256 + threadIdx.x;
    if (e < E) {
        int d = dst[e];
        int pos = row_ptr[d] + atomicAdd(&cursor[d], 1);
        col_src[pos] = src[e];
    }
}

// ---------------- fused BN-affine + dual GEMM: fs/fd = affine(h) @ W + b ----------------
// grid: (ceil(N/64), 8); y<4 -> fs col-tiles, y>=4 -> fd col-tiles. 64x64 out tile, K=64.

__global__ void __launch_bounds__(256) gemm_kernel(
    const float* __restrict__ h, const float* __restrict__ bnA, const float* __restrict__ bnB,
    const float* __restrict__ Wsrc, const float* __restrict__ bsrc,
    const float* __restrict__ Wdst, const float* __restrict__ bdst,
    float* __restrict__ fs, float* __restrict__ fd, int N)
{
    __shared__ __align__(16) float hsT[64][68];     // hsT[k][r], stride 68 keeps rows 16B-aligned
    __shared__ __align__(16) float wt[16][65][4];   // wt[tc][k][j] = W[k][c0+4*tc+j]
    int t = threadIdx.x;
    int row0 = blockIdx.x * 64;
    int yt = blockIdx.y;
    const float* W    = (yt < 4) ? Wsrc : Wdst;
    const float* bias = (yt < 4) ? bsrc : bdst;
    float* out        = (yt < 4) ? fs : fd;
    int c0 = (yt & 3) * 64;

#pragma unroll
    for (int i = 0; i < 16; i++) {
        int flat = i * 256 + t;
        int r = flat >> 6, k = flat & 63;
        int gr = row0 + r;
        float v = 0.f;
        if (gr < N) v = h[(size_t)gr * 64 + k] * bnA[k] + bnB[k];
        hsT[k][r] = v;
    }
#pragma unroll
    for (int i = 0; i < 16; i++) {
        int flat = i * 256 + t;
        int k = flat >> 6, c = flat & 63;
        wt[c >> 2][k][c & 3] = W[k * 256 + c0 + c];
    }
    __syncthreads();

    int tc = t & 15, tr = t >> 4;
    float4 bv = *(const float4*)(bias + c0 + 4 * tc);
    float acc[4][4];
#pragma unroll
    for (int i = 0; i < 4; i++) {
        acc[i][0] = bv.x; acc[i][1] = bv.y; acc[i][2] = bv.z; acc[i][3] = bv.w;
    }
#pragma unroll 8
    for (int k = 0; k < 64; k++) {
        float4 a = *(const float4*)&hsT[k][4 * tr];
        float4 b = *(const float4*)&wt[tc][k][0];
        acc[0][0] = fmaf(a.x, b.x, acc[0][0]); acc[0][1] = fmaf(a.x, b.y, acc[0][1]);
        acc[0][2] = fmaf(a.x, b.z, acc[0][2]); acc[0][3] = fmaf(a.x, b.w, acc[0][3]);
        acc[1][0] = fmaf(a.y, b.x, acc[1][0]); acc[1][1] = fmaf(a.y, b.y, acc[1][1]);
        acc[1][2] = fmaf(a.y, b.z, acc[1][2]); acc[1][3] = fmaf(a.y, b.w, acc[1][3]);
        acc[2][0] = fmaf(a.z, b.x, acc[2][0]); acc[2][1] = fmaf(a.z, b.y, acc[2][1]);
        acc[2][2] = fmaf(a.z, b.z, acc[2][2]); acc[2][3] = fmaf(a.z, b.w, acc[2][3]);
        acc[3][0] = fmaf(a.w, b.x, acc[3][0]); acc[3][1] = fmaf(a.w, b.y, acc[3][1]);
        acc[3][2] = fmaf(a.w, b.z, acc[3][2]); acc[3][3] = fmaf(a.w, b.w, acc[3][3]);
    }
#pragma unroll
    for (int i = 0; i < 4; i++) {
        int gr = row0 + 4 * tr + i;
        if (gr < N)
            *(float4*)(out + (size_t)gr * 256 + c0 + 4 * tc) =
                make_float4(acc[i][0], acc[i][1], acc[i][2], acc[i][3]);
    }
}

// ---------------- fused GATv2 edge phase: one wave per dst node ----------------
// lane = e4*16+dg: e4 = edge slot (4 edges/iter), dg = dim group (4 dims each).
// Single pass: logits (no max; alpha invariant, logits O(1)), exp-weighted sums,
// divide at end, relu, head-mean. Writes hmean [N,64] (raw, pre-BN).

__global__ void __launch_bounds__(256) gat_kernel(
    const float* __restrict__ fs, const float* __restrict__ fd,
    const float* __restrict__ attn,
    const int* __restrict__ row_ptr, const int* __restrict__ col_src,
    float* __restrict__ hmean, int N)
{
    int wid = (blockIdx.x << 2) + (threadIdx.x >> 6);
    if (wid >= N) return;
    int lane = threadIdx.x & 63;
    int e4 = lane >> 4;
    int dg = lane & 15;
    int rs = row_ptr[wid];
    int deg = row_ptr[wid + 1] - rs;

    float4 att[NH], fdv[NH];
#pragma unroll
    for (int h = 0; h < NH; h++) {
        att[h] = *(const float4*)(attn + h * 64 + dg * 4);
        fdv[h] = *(const float4*)(fd + (size_t)wid * 256 + h * 64 + dg * 4);
    }
    float4 acc[NH];
    float l[NH];
#pragma unroll
    for (int h = 0; h < NH; h++) { acc[h] = make_float4(0.f, 0.f, 0.f, 0.f); l[h] = 0.f; }

    int s_reg = 0;
    if (lane < deg) s_reg = col_src[rs + lane];   // prefetch up to 64 srcs into lanes

    for (int i = 0; i < deg; i += 4) {
        int idx = i + e4;
        bool valid = idx < deg;
        int cidx = valid ? idx : (deg - 1);
        int sh = __shfl(s_reg, min(cidx, 63), 64);
        int s;
        if (cidx < 64) s = sh; else s = col_src[rs + cidx];
        const float* fsp = fs + (size_t)s * 256;
#pragma unroll
        for (int h = 0; h < NH; h++) {
            float4 v = *(const float4*)(fsp + h * 64 + dg * 4);
            float x0 = v.x + fdv[h].x, x1 = v.y + fdv[h].y;
            float x2 = v.z + fdv[h].z, x3 = v.w + fdv[h].w;
            x0 = fmaxf(x0, 0.2f * x0); x1 = fmaxf(x1, 0.2f * x1);
            x2 = fmaxf(x2, 0.2f * x2); x3 = fmaxf(x3, 0.2f * x3);
            float p = x0 * att[h].x + x1 * att[h].y + x2 * att[h].z + x3 * att[h].w;
            p += __shfl_xor(p, 1); p += __shfl_xor(p, 2);
            p += __shfl_xor(p, 4); p += __shfl_xor(p, 8);     // sum over 16 dg lanes
            float e = valid ? __expf(p) : 0.f;
            l[h] += e;
            acc[h].x = fmaf(e, v.x, acc[h].x);
            acc[h].y = fmaf(e, v.y, acc[h].y);
            acc[h].z = fmaf(e, v.z, acc[h].z);
            acc[h].w = fmaf(e, v.w, acc[h].w);
        }
    }
    // reduce over edge-slot groups (lane bits 4,5)
#pragma unroll
    for (int h = 0; h < NH; h++) {
#pragma unroll
        for (int off = 16; off <= 32; off <<= 1) {
            l[h] += __shfl_xor(l[h], off);
            acc[h].x += __shfl_xor(acc[h].x, off);
            acc[h].y += __shfl_xor(acc[h].y, off);
            acc[h].z += __shfl_xor(acc[h].z, off);
            acc[h].w += __shfl_xor(acc[h].w, off);
        }
    }
    if (e4 == 0) {
        float4 hm = make_float4(0.f, 0.f, 0.f, 0.f);
#pragma unroll
        for (int h = 0; h < NH; h++) {
            float inv = (l[h] > 0.f) ? 1.f / l[h] : 0.f;
            hm.x += fmaxf(acc[h].x * inv, 0.f);
            hm.y += fmaxf(acc[h].y * inv, 0.f);
            hm.z += fmaxf(acc[h].z * inv, 0.f);
            hm.w += fmaxf(acc[h].w * inv, 0.f);
        }
        hm.x *= 0.25f; hm.y *= 0.25f; hm.z *= 0.25f; hm.w *= 0.25f;
        *(float4*)(hmean + (size_t)wid * 64 + dg * 4) = hm;
    }
}

// ---------------- BN stats + graph segment sums (raw hmean) ----------------
// 128 blocks x 4 waves; wave handles a contiguous node chunk; lane = feature.
// graph_ids sorted -> run-length accumulate, flush atomics only on boundary.

__global__ void __launch_bounds__(256) stats_kernel(
    const float* __restrict__ hmean, const int* __restrict__ gid,
    float* __restrict__ bnsum, float* __restrict__ bnsumsq,
    float* __restrict__ S, int N)
{
    __shared__ float bs[4][64], bq[4][64];
    int t = threadIdx.x, lane = t & 63, w = t >> 6;
    int wglobal = blockIdx.x * 4 + w;
    int chunk = (N + 511) >> 9;
    int n0 = wglobal * chunk;
    int n1 = min(n0 + chunk, N);
    float sum = 0.f, sq = 0.f, run = 0.f;
    int cur = -1;
    for (int n = n0; n < n1; n++) {
        float v = hmean[(size_t)n * 64 + lane];
        int g = gid[n];
        if (g != cur) {
            if (cur >= 0) atomicAdd(&S[cur * 64 + lane], run);
            run = 0.f;
            cur = g;
        }
        run += v;
        sum += v;
        sq = fmaf(v, v, sq);
    }
    if (cur >= 0) atomicAdd(&S[cur * 64 + lane], run);
    bs[w][lane] = sum;
    bq[w][lane] = sq;
    __syncthreads();
    if (w == 0) {
        float s2 = bs[0][lane] + bs[1][lane] + bs[2][lane] + bs[3][lane];
        float q2 = bq[0][lane] + bq[1][lane] + bq[2][lane] + bq[3][lane];
        atomicAdd(&bnsum[lane], s2);
        atomicAdd(&bnsumsq[lane], q2);
    }
}

// ---------------- per-layer small stage: BN affine, pooled MLP + BN -> p_l ----------------

__global__ void __launch_bounds__(256) pooled_kernel(
    const float* __restrict__ bnsum, const float* __restrict__ bnsumsq,
    const float* __restrict__ S, const int* __restrict__ cntg,
    const float* __restrict__ bn_g, const float* __restrict__ bn_b,
    const float* __restrict__ lpW, const float* __restrict__ lpb,
    const float* __restrict__ lpg, const float* __restrict__ lpbt,
    float* __restrict__ bnA_out, float* __restrict__ bnB_out,
    float* __restrict__ p_out, int N)
{
    __shared__ float A[64], B[64];
    __shared__ float q[128][64];
    __shared__ float mu2[64], sc2[64];
    int t = threadIdx.x;
    if (t < 64) {
        float mu = bnsum[t] / (float)N;
        float var = bnsumsq[t] / (float)N - mu * mu;
        float a = bn_g[t] / sqrtf(var + 1e-5f);
        float b = bn_b[t] - mu * a;
        A[t] = a; B[t] = b;
        bnA_out[t] = a; bnB_out[t] = b;
    }
    __syncthreads();
    int f = t & 63, g0 = t >> 6;
    for (int j = 0; j < 32; j++) {
        int g = g0 + 4 * j;
        float cg = (float)cntg[g];
        float s = lpb[f];
        for (int k = 0; k < 64; k++) {
            float pb = A[k] * S[g * 64 + k] + B[k] * cg;   // pooled, BN folded
            s = fmaf(pb, lpW[k * 64 + f], s);
        }
        q[g][f] = fmaxf(s, 0.f);
    }
    __syncthreads();
    if (t < 64) {
        float m = 0.f;
        for (int g = 0; g < 128; g++) m += q[g][t];
        m *= (1.f / 128.f);
        float v = 0.f;
        for (int g = 0; g < 128; g++) { float d = q[g][t] - m; v = fmaf(d, d, v); }
        v *= (1.f / 128.f);
        mu2[t] = m;
        sc2[t] = lpg[t] / sqrtf(v + 1e-5f);
    }
    __syncthreads();
    for (int i = t; i < 128 * 64; i += 256) {
        int g = i >> 6, ff = i & 63;
        p_out[i] = (q[g][ff] - mu2[ff]) * sc2[ff] + lpbt[ff];
    }
}

// ---------------- final head: cat -> linear+BN -> linear+BN -> log_softmax ----------------

__global__ void __launch_bounds__(256) final_kernel(
    const float* __restrict__ p,
    const float* __restrict__ blW, const float* __restrict__ blb,
    const float* __restrict__ blg, const float* __restrict__ blbt,
    const float* __restrict__ llW, const float* __restrict__ llb,
    const float* __restrict__ llg, const float* __restrict__ llbt,
    float* __restrict__ out)
{
    __shared__ float hh[128][64];
    __shared__ float ph[128][12];
    __shared__ float mu[64], sc[64];
    __shared__ float mj[12], scj[12];
    int t = threadIdx.x;
    int f = t & 63, g0 = t >> 6;
    for (int j = 0; j < 32; j++) {
        int g = g0 + 4 * j;
        float s = blb[f];
        for (int k = 0; k < 192; k++) {
            float c = p[(k >> 6) * 8192 + g * 64 + (k & 63)];
            s = fmaf(c, blW[k * 64 + f], s);
        }
        hh[g][f] = fmaxf(s, 0.f);
    }
    __syncthreads();
    if (t < 64) {
        float m = 0.f;
        for (int g = 0; g < 128; g++) m += hh[g][t];
        m *= (1.f / 128.f);
        float v = 0.f;
        for (int g = 0; g < 128; g++) { float d = hh[g][t] - m; v = fmaf(d, d, v); }
        v *= (1.f / 128.f);
        mu[t] = m;
        sc[t] = blg[t] / sqrtf(v + 1e-5f);
    }
    __syncthreads();
    for (int i = t; i < 8192; i += 256) {
        int g = i >> 6, ff = i & 63;
        float v = (hh[g][ff] - mu[ff]) * sc[ff] + blbt[ff];
        out[1280 + i] = v;      // output 1: pooled_hh
        hh[g][ff] = v;
    }
    __syncthreads();
    for (int i = t; i < 1280; i += 256) {
        int g = i / 10, j = i - g * 10;
        float s = llb[j];
        for (int k = 0; k < 64; k++) s = fmaf(hh[g][k], llW[k * 10 + j], s);
        ph[g][j] = fmaxf(s, 0.f);
    }
    __syncthreads();
    if (t < 10) {
        float m = 0.f;
        for (int g = 0; g < 128; g++) m += ph[g][t];
        m *= (1.f / 128.f);
        float v = 0.f;
        for (int g = 0; g < 128; g++) { float d = ph[g][t] - m; v = fmaf(d, d, v); }
        v *= (1.f / 128.f);
        mj[t] = m;
        scj[t] = llg[t] / sqrtf(v + 1e-5f);
    }
    __syncthreads();
    if (t < 128) {
        float vals[10];
        float mx = -1e30f;
        for (int j = 0; j < 10; j++) {
            vals[j] = (ph[t][j] - mj[j]) * scj[j] + llbt[j];
            mx = fmaxf(mx, vals[j]);
        }
        float se = 0.f;
        for (int j = 0; j < 10; j++) se += __expf(vals[j] - mx);
        float lse = logf(se) + mx;
        for (int j = 0; j < 10; j++) out[t * 10 + j] = vals[j] - lse;   // output 0: log_softmax
    }
}

// ---------------- launcher ----------------

extern "C" void kernel_launch(void* const* d_in, const int* in_sizes, int n_in,
                              void* d_out, int out_size, void* d_ws, size_t ws_size,
                              hipStream_t stream)
{
    const float* feat = (const float*)d_in[0];
    const float* Wsrc = (const float*)d_in[1];
    const float* bsrc = (const float*)d_in[2];
    const float* Wdst = (const float*)d_in[3];
    const float* bdst = (const float*)d_in[4];
    const float* attn = (const float*)d_in[5];
    const float* bn_g = (const float*)d_in[6];
    const float* bn_b = (const float*)d_in[7];
    const float* lpW  = (const float*)d_in[8];
    const float* lpb  = (const float*)d_in[9];
    const float* lpg  = (const float*)d_in[10];
    const float* lpbt = (const float*)d_in[11];
    const float* blW  = (const float*)d_in[12];
    const float* blb  = (const float*)d_in[13];
    const float* blg  = (const float*)d_in[14];
    const float* blbt = (const float*)d_in[15];
    const float* llW  = (const float*)d_in[16];
    const float* llb  = (const float*)d_in[17];
    const float* llg  = (const float*)d_in[18];
    const float* llbt = (const float*)d_in[19];
    const int* srcp = (const int*)d_in[20];
    const int* dstp = (const int*)d_in[21];
    const int* gidp = (const int*)d_in[22];
    float* out = (float*)d_out;

    int N = in_sizes[0] / 64;
    int E = in_sizes[20];

    // workspace layout (all re-initialized every call)
    float* wsf   = (float*)d_ws;
    float* fs    = wsf;                              // N*256
    float* fd    = fs + (size_t)N * 256;             // N*256
    float* hmean = fd + (size_t)N * 256;             // N*64
    float* pbuf  = hmean + (size_t)N * 64;           // 3*128*64
    float* bnA   = pbuf + 3 * 8192;                  // 4*64
    float* bnB   = bnA + 256;                        // 4*64
    float* zstart = bnB + 256;
    float* bnsum = zstart;                           // 3*64
    float* bnsq  = bnsum + 192;                      // 3*64
    float* S     = bnsq + 192;                       // 3*128*64
    int* deg     = (int*)(S + 3 * 8192);             // N
    int* cursor  = deg + N;                          // N
    int* cntg    = cursor + N;                       // 128
    int* zend    = cntg + 128;
    int* row_ptr = zend;                             // N+1
    int* col_src = row_ptr + (N + 1);                // E

    size_t zbytes = (size_t)((char*)zend - (char*)zstart);
    hipMemsetAsync(zstart, 0, zbytes, stream);
    hipLaunchKernelGGL(init_affine_kernel, dim3(1), dim3(64), 0, stream, bnA, bnB);
    hipLaunchKernelGGL(hist_kernel, dim3((E + 255) / 256), dim3(256), 0, stream, dstp, deg, E);
    hipLaunchKernelGGL(cntg_kernel, dim3((N + 255) / 256), dim3(256), 0, stream, gidp, cntg, N);
    hipLaunchKernelGGL(scan_kernel, dim3(1), dim3(1024), 0, stream, deg, row_ptr, N);
    hipLaunchKernelGGL(scatter_kernel, dim3((E + 255) / 256), dim3(256), 0, stream,
                       srcp, dstp, row_ptr, cursor, col_src, E);

    for (int l = 0; l < 3; l++) {
        const float* hsrcp = (l == 0) ? feat : hmean;
        hipLaunchKernelGGL(gemm_kernel, dim3((N + 63) / 64, 8), dim3(256), 0, stream,
                           hsrcp, bnA + l * 64, bnB + l * 64,
                           Wsrc + (size_t)l * 64 * 256, bsrc + l * 256,
                           Wdst + (size_t)l * 64 * 256, bdst + l * 256, fs, fd, N);
        hipLaunchKernelGGL(gat_kernel, dim3((N + 3) / 4), dim3(256), 0, stream,
                           fs, fd, attn + l * 256, row_ptr, col_src, hmean, N);
        hipLaunchKernelGGL(stats_kernel, dim3(128), dim3(256), 0, stream,
                           hmean, gidp, bnsum + l * 64, bnsq + l * 64, S + l * 8192, N);
        hipLaunchKernelGGL(pooled_kernel, dim3(1), dim3(256), 0, stream,
                           bnsum + l * 64, bnsq + l * 64, S + l * 8192, cntg,
                           bn_g + l * 64, bn_b + l * 64,
                           lpW + (size_t)l * 64 * 64, lpb + l * 64, lpg + l * 64, lpbt + l * 64,
                           bnA + (l + 1) * 64, bnB + (l + 1) * 64, pbuf + l * 8192, N);
    }
    hipLaunchKernelGGL(final_kernel, dim3(1), dim3(256), 0, stream,
                       pbuf, blW, blb, blg, blbt, llW, llb, llg, llbt, out);
}

// Round 2
// 997.032 us; speedup vs baseline: 1.3551x; 1.3551x over previous
//
#include <hip/hip_runtime.h>
#include <cmath>

#define NH 4

// ---------------- init / CSR build ----------------

__global__ void __launch_bounds__(64) init_affine_kernel(float* bnA, float* bnB) {
    int t = threadIdx.x;
    bnA[t] = 1.f;
    bnB[t] = 0.f;
}

__global__ void __launch_bounds__(256) hist_kernel(const int* __restrict__ dst,
                                                   int* __restrict__ deg, int E) {
    int e = blockIdx.x * 256 + threadIdx.x;
    if (e < E) atomicAdd(&deg[dst[e]], 1);
}

__global__ void __launch_bounds__(256) cntg_kernel(const int* __restrict__ gid,
                                                   int* __restrict__ cntg, int N) {
    int n = blockIdx.x * 256 + threadIdx.x;
    if (n < N) atomicAdd(&cntg[gid[n]], 1);
}

// 3-phase exclusive scan of deg[N] -> row_ptr[N+1]
__global__ void __launch_bounds__(256) scan_sums_kernel(const int* __restrict__ deg,
                                                        int* __restrict__ bsum, int N) {
    __shared__ int red[256];
    int t = threadIdx.x;
    int base = blockIdx.x * 1024 + t * 4;
    int s = 0;
#pragma unroll
    for (int j = 0; j < 4; j++) { int i = base + j; if (i < N) s += deg[i]; }
    red[t] = s;
    __syncthreads();
    for (int off = 128; off > 0; off >>= 1) {
        if (t < off) red[t] += red[t + off];
        __syncthreads();
    }
    if (t == 0) bsum[blockIdx.x] = red[0];
}

__global__ void scan_offsets_kernel(const int* __restrict__ bsum, int* __restrict__ boff,
                                    int* __restrict__ row_ptr_N, int nb) {
    if (threadIdx.x == 0) {
        int acc = 0;
        for (int b = 0; b < nb; b++) { boff[b] = acc; acc += bsum[b]; }
        row_ptr_N[0] = acc;
    }
}

__global__ void __launch_bounds__(256) scan_final_kernel(const int* __restrict__ deg,
                                                         const int* __restrict__ boff,
                                                         int* __restrict__ row_ptr, int N) {
    __shared__ int red[256];
    int t = threadIdx.x;
    int base = blockIdx.x * 1024 + t * 4;
    int d[4];
    int s = 0;
#pragma unroll
    for (int j = 0; j < 4; j++) {
        int i = base + j;
        d[j] = (i < N) ? deg[i] : 0;
        s += d[j];
    }
    red[t] = s;
    __syncthreads();
    for (int off = 1; off < 256; off <<= 1) {
        int v = (t >= off) ? red[t - off] : 0;
        __syncthreads();
        red[t] += v;
        __syncthreads();
    }
    int excl = red[t] - s + boff[blockIdx.x];
#pragma unroll
    for (int j = 0; j < 4; j++) {
        int i = base + j;
        if (i < N) row_ptr[i] = excl;
        excl += d[j];
    }
}

__global__ void __launch_bounds__(256) scatter_kernel(const int* __restrict__ src,
                                                      const int* __restrict__ dst,
                                                      const int* __restrict__ row_ptr,
                                                      int* __restrict__ cursor,
                                                      int* __restrict__ col_src, int E) {
    int e = blockIdx.x * 256 + threadIdx.x;
    if (e < E) {
        int d = dst[e];
        int pos = row_ptr[d] + atomicAdd(&cursor[d], 1);
        col_src[pos] = src[e];
    }
}

// ---------------- fused BN-affine + dual GEMM: fs/fd = affine(h) @ W + b ----------------

__global__ void __launch_bounds__(256) gemm_kernel(
    const float* __restrict__ h, const float* __restrict__ bnA, const float* __restrict__ bnB,
    const float* __restrict__ Wsrc, const float* __restrict__ bsrc,
    const float* __restrict__ Wdst, const float* __restrict__ bdst,
    float* __restrict__ fs, float* __restrict__ fd, int N)
{
    __shared__ __align__(16) float hsT[64][68];
    __shared__ __align__(16) float wt[16][65][4];
    int t = threadIdx.x;
    int row0 = blockIdx.x * 64;
    int yt = blockIdx.y;
    const float* W    = (yt < 4) ? Wsrc : Wdst;
    const float* bias = (yt < 4) ? bsrc : bdst;
    float* out        = (yt < 4) ? fs : fd;
    int c0 = (yt & 3) * 64;

#pragma unroll
    for (int i = 0; i < 16; i++) {
        int flat = i * 256 + t;
        int r = flat >> 6, k = flat & 63;
        int gr = row0 + r;
        float v = 0.f;
        if (gr < N) v = h[(size_t)gr * 64 + k] * bnA[k] + bnB[k];
        hsT[k][r] = v;
    }
#pragma unroll
    for (int i = 0; i < 16; i++) {
        int flat = i * 256 + t;
        int k = flat >> 6, c = flat & 63;
        wt[c >> 2][k][c & 3] = W[k * 256 + c0 + c];
    }
    __syncthreads();

    int tc = t & 15, tr = t >> 4;
    float4 bv = *(const float4*)(bias + c0 + 4 * tc);
    float acc[4][4];
#pragma unroll
    for (int i = 0; i < 4; i++) {
        acc[i][0] = bv.x; acc[i][1] = bv.y; acc[i][2] = bv.z; acc[i][3] = bv.w;
    }
#pragma unroll 8
    for (int k = 0; k < 64; k++) {
        float4 a = *(const float4*)&hsT[k][4 * tr];
        float4 b = *(const float4*)&wt[tc][k][0];
        acc[0][0] = fmaf(a.x, b.x, acc[0][0]); acc[0][1] = fmaf(a.x, b.y, acc[0][1]);
        acc[0][2] = fmaf(a.x, b.z, acc[0][2]); acc[0][3] = fmaf(a.x, b.w, acc[0][3]);
        acc[1][0] = fmaf(a.y, b.x, acc[1][0]); acc[1][1] = fmaf(a.y, b.y, acc[1][1]);
        acc[1][2] = fmaf(a.y, b.z, acc[1][2]); acc[1][3] = fmaf(a.y, b.w, acc[1][3]);
        acc[2][0] = fmaf(a.z, b.x, acc[2][0]); acc[2][1] = fmaf(a.z, b.y, acc[2][1]);
        acc[2][2] = fmaf(a.z, b.z, acc[2][2]); acc[2][3] = fmaf(a.z, b.w, acc[2][3]);
        acc[3][0] = fmaf(a.w, b.x, acc[3][0]); acc[3][1] = fmaf(a.w, b.y, acc[3][1]);
        acc[3][2] = fmaf(a.w, b.z, acc[3][2]); acc[3][3] = fmaf(a.w, b.w, acc[3][3]);
    }
#pragma unroll
    for (int i = 0; i < 4; i++) {
        int gr = row0 + 4 * tr + i;
        if (gr < N)
            *(float4*)(out + (size_t)gr * 256 + c0 + 4 * tc) =
                make_float4(acc[i][0], acc[i][1], acc[i][2], acc[i][3]);
    }
}

// ---------------- fused GATv2 edge phase: one wave per dst node ----------------

__global__ void __launch_bounds__(256) gat_kernel(
    const float* __restrict__ fs, const float* __restrict__ fd,
    const float* __restrict__ attn,
    const int* __restrict__ row_ptr, const int* __restrict__ col_src,
    float* __restrict__ hmean, int N)
{
    int wid = (blockIdx.x << 2) + (threadIdx.x >> 6);
    if (wid >= N) return;
    int lane = threadIdx.x & 63;
    int e4 = lane >> 4;
    int dg = lane & 15;
    int rs = row_ptr[wid];
    int deg = row_ptr[wid + 1] - rs;

    float4 att[NH], fdv[NH];
#pragma unroll
    for (int h = 0; h < NH; h++) {
        att[h] = *(const float4*)(attn + h * 64 + dg * 4);
        fdv[h] = *(const float4*)(fd + (size_t)wid * 256 + h * 64 + dg * 4);
    }
    float4 acc[NH];
    float l[NH];
#pragma unroll
    for (int h = 0; h < NH; h++) { acc[h] = make_float4(0.f, 0.f, 0.f, 0.f); l[h] = 0.f; }

    int s_reg = 0;
    if (lane < deg) s_reg = col_src[rs + lane];

    for (int i = 0; i < deg; i += 4) {
        int idx = i + e4;
        bool valid = idx < deg;
        int cidx = valid ? idx : (deg - 1);
        int sh = __shfl(s_reg, min(cidx, 63), 64);
        int s;
        if (cidx < 64) s = sh; else s = col_src[rs + cidx];
        const float* fsp = fs + (size_t)s * 256;
#pragma unroll
        for (int h = 0; h < NH; h++) {
            float4 v = *(const float4*)(fsp + h * 64 + dg * 4);
            float x0 = v.x + fdv[h].x, x1 = v.y + fdv[h].y;
            float x2 = v.z + fdv[h].z, x3 = v.w + fdv[h].w;
            x0 = fmaxf(x0, 0.2f * x0); x1 = fmaxf(x1, 0.2f * x1);
            x2 = fmaxf(x2, 0.2f * x2); x3 = fmaxf(x3, 0.2f * x3);
            float p = x0 * att[h].x + x1 * att[h].y + x2 * att[h].z + x3 * att[h].w;
            p += __shfl_xor(p, 1); p += __shfl_xor(p, 2);
            p += __shfl_xor(p, 4); p += __shfl_xor(p, 8);
            float e = valid ? __expf(p) : 0.f;
            l[h] += e;
            acc[h].x = fmaf(e, v.x, acc[h].x);
            acc[h].y = fmaf(e, v.y, acc[h].y);
            acc[h].z = fmaf(e, v.z, acc[h].z);
            acc[h].w = fmaf(e, v.w, acc[h].w);
        }
    }
#pragma unroll
    for (int h = 0; h < NH; h++) {
#pragma unroll
        for (int off = 16; off <= 32; off <<= 1) {
            l[h] += __shfl_xor(l[h], off);
            acc[h].x += __shfl_xor(acc[h].x, off);
            acc[h].y += __shfl_xor(acc[h].y, off);
            acc[h].z += __shfl_xor(acc[h].z, off);
            acc[h].w += __shfl_xor(acc[h].w, off);
        }
    }
    if (e4 == 0) {
        float4 hm = make_float4(0.f, 0.f, 0.f, 0.f);
#pragma unroll
        for (int h = 0; h < NH; h++) {
            float inv = (l[h] > 0.f) ? 1.f / l[h] : 0.f;
            hm.x += fmaxf(acc[h].x * inv, 0.f);
            hm.y += fmaxf(acc[h].y * inv, 0.f);
            hm.z += fmaxf(acc[h].z * inv, 0.f);
            hm.w += fmaxf(acc[h].w * inv, 0.f);
        }
        hm.x *= 0.25f; hm.y *= 0.25f; hm.z *= 0.25f; hm.w *= 0.25f;
        *(float4*)(hmean + (size_t)wid * 64 + dg * 4) = hm;
    }
}

// ---------------- BN stats + graph segment sums (raw hmean) ----------------

__global__ void __launch_bounds__(256) stats_kernel(
    const float* __restrict__ hmean, const int* __restrict__ gid,
    float* __restrict__ bnsum, float* __restrict__ bnsumsq,
    float* __restrict__ S, int N)
{
    __shared__ float bs[4][64], bq[4][64];
    int t = threadIdx.x, lane = t & 63, w = t >> 6;
    int wglobal = blockIdx.x * 4 + w;
    int chunk = (N + 511) >> 9;
    int n0 = wglobal * chunk;
    int n1 = min(n0 + chunk, N);
    float sum = 0.f, sq = 0.f, run = 0.f;
    int cur = -1;
    for (int n = n0; n < n1; n++) {
        float v = hmean[(size_t)n * 64 + lane];
        int g = gid[n];
        if (g != cur) {
            if (cur >= 0) atomicAdd(&S[cur * 64 + lane], run);
            run = 0.f;
            cur = g;
        }
        run += v;
        sum += v;
        sq = fmaf(v, v, sq);
    }
    if (cur >= 0) atomicAdd(&S[cur * 64 + lane], run);
    bs[w][lane] = sum;
    bq[w][lane] = sq;
    __syncthreads();
    if (w == 0) {
        float s2 = bs[0][lane] + bs[1][lane] + bs[2][lane] + bs[3][lane];
        float q2 = bq[0][lane] + bq[1][lane] + bq[2][lane] + bq[3][lane];
        atomicAdd(&bnsum[lane], s2);
        atomicAdd(&bnsumsq[lane], q2);
    }
}

// ---------------- pooled path A: per-graph MLP row (128 blocks) ----------------
// q[g][f] = relu(lpb[f] + sum_k (A[k]*S[g][k]+B[k]*cnt[g]) * lpW[k][f]);  qsum/qsq atomics.

__global__ void __launch_bounds__(256) pooled_a_kernel(
    const float* __restrict__ bnsum, const float* __restrict__ bnsumsq,
    const float* __restrict__ S, const int* __restrict__ cntg,
    const float* __restrict__ bn_g, const float* __restrict__ bn_b,
    const float* __restrict__ lpW, const float* __restrict__ lpb,
    float* __restrict__ q, float* __restrict__ qsum, float* __restrict__ qsq, int N)
{
    __shared__ float sv[64];
    __shared__ float partial[4][64];
    int g = blockIdx.x;
    int t = threadIdx.x;
    if (t < 64) {
        float mu = bnsum[t] / (float)N;
        float var = bnsumsq[t] / (float)N - mu * mu;
        float a = bn_g[t] / sqrtf(var + 1e-5f);
        float b = bn_b[t] - mu * a;
        sv[t] = a * S[g * 64 + t] + b * (float)cntg[g];
    }
    __syncthreads();
    int f = t & 63, kc = t >> 6;
    float acc = 0.f;
#pragma unroll
    for (int k = kc * 16; k < kc * 16 + 16; k++)
        acc = fmaf(sv[k], lpW[k * 64 + f], acc);
    partial[kc][f] = acc;
    __syncthreads();
    if (t < 64) {
        float v = partial[0][t] + partial[1][t] + partial[2][t] + partial[3][t] + lpb[t];
        v = fmaxf(v, 0.f);
        q[g * 64 + t] = v;
        atomicAdd(&qsum[t], v);
        atomicAdd(&qsq[t], v * v);
    }
}

// ---------------- pooled path B: BN over graphs + next-layer node-BN affine ----------------

__global__ void __launch_bounds__(256) pooled_b_kernel(
    const float* __restrict__ bnsum, const float* __restrict__ bnsumsq,
    const float* __restrict__ q, const float* __restrict__ qsum, const float* __restrict__ qsq,
    const float* __restrict__ bn_g, const float* __restrict__ bn_b,
    const float* __restrict__ lpg, const float* __restrict__ lpbt,
    float* __restrict__ bnA_out, float* __restrict__ bnB_out,
    float* __restrict__ p_out, int N)
{
    __shared__ float mu2[64], sc2[64];
    int t = threadIdx.x;
    if (t < 64) {
        float mu = bnsum[t] / (float)N;
        float var = bnsumsq[t] / (float)N - mu * mu;
        float a = bn_g[t] / sqrtf(var + 1e-5f);
        bnA_out[t] = a;
        bnB_out[t] = bn_b[t] - mu * a;
        float m = qsum[t] * (1.f / 128.f);
        float v = qsq[t] * (1.f / 128.f) - m * m;
        mu2[t] = m;
        sc2[t] = lpg[t] / sqrtf(v + 1e-5f);
    }
    __syncthreads();
    for (int i = t; i < 128 * 64; i += 256) {
        int ff = i & 63;
        p_out[i] = (q[i] - mu2[ff]) * sc2[ff] + lpbt[ff];
    }
}

// ---------------- head A: hh = relu(cat @ blW + blb), 128 blocks, stats atomics ----------------

__global__ void __launch_bounds__(256) head_gemm_kernel(
    const float* __restrict__ p, const float* __restrict__ blW, const float* __restrict__ blb,
    float* __restrict__ hh, float* __restrict__ hsum, float* __restrict__ hsq)
{
    __shared__ float cat[192];
    __shared__ float partial[4][64];
    int g = blockIdx.x;
    int t = threadIdx.x;
    if (t < 192) cat[t] = p[(t >> 6) * 8192 + g * 64 + (t & 63)];
    __syncthreads();
    int f = t & 63, kc = t >> 6;
    float acc = 0.f;
#pragma unroll
    for (int k = kc * 48; k < kc * 48 + 48; k++)
        acc = fmaf(cat[k], blW[k * 64 + f], acc);
    partial[kc][f] = acc;
    __syncthreads();
    if (t < 64) {
        float v = partial[0][t] + partial[1][t] + partial[2][t] + partial[3][t] + blb[t];
        v = fmaxf(v, 0.f);
        hh[g * 64 + t] = v;
        atomicAdd(&hsum[t], v);
        atomicAdd(&hsq[t], v * v);
    }
}

// ---------------- head B: BN, second linear, BN, log_softmax ----------------

__global__ void __launch_bounds__(256) head_finish_kernel(
    const float* __restrict__ hh, const float* __restrict__ hsum, const float* __restrict__ hsq,
    const float* __restrict__ blg, const float* __restrict__ blbt,
    const float* __restrict__ llW, const float* __restrict__ llb,
    const float* __restrict__ llg, const float* __restrict__ llbt,
    float* __restrict__ out)
{
    __shared__ float hn[128][65];
    __shared__ float ph[128][12];
    __shared__ float mu[64], sc[64];
    __shared__ float mj[12], scj[12];
    __shared__ float sW[640];
    int t = threadIdx.x;
    if (t < 64) {
        float m = hsum[t] * (1.f / 128.f);
        float v = hsq[t] * (1.f / 128.f) - m * m;
        mu[t] = m;
        sc[t] = blg[t] / sqrtf(v + 1e-5f);
    }
    for (int i = t; i < 640; i += 256) sW[i] = llW[i];
    __syncthreads();
    for (int i = t; i < 8192; i += 256) {
        int g = i >> 6, ff = i & 63;
        float v = (hh[i] - mu[ff]) * sc[ff] + blbt[ff];
        out[1280 + i] = v;          // output 1: pooled_hh
        hn[g][ff] = v;
    }
    __syncthreads();
    for (int i = t; i < 1280; i += 256) {
        int g = i / 10, j = i - g * 10;
        float s = llb[j];
#pragma unroll 8
        for (int k = 0; k < 64; k++) s = fmaf(hn[g][k], sW[k * 10 + j], s);
        ph[g][j] = fmaxf(s, 0.f);
    }
    __syncthreads();
    if (t < 10) {
        float m = 0.f;
        for (int g = 0; g < 128; g++) m += ph[g][t];
        m *= (1.f / 128.f);
        float v = 0.f;
        for (int g = 0; g < 128; g++) { float d = ph[g][t] - m; v = fmaf(d, d, v); }
        v *= (1.f / 128.f);
        mj[t] = m;
        scj[t] = llg[t] / sqrtf(v + 1e-5f);
    }
    __syncthreads();
    if (t < 128) {
        float vals[10];
        float mx = -1e30f;
        for (int j = 0; j < 10; j++) {
            vals[j] = (ph[t][j] - mj[j]) * scj[j] + llbt[j];
            mx = fmaxf(mx, vals[j]);
        }
        float se = 0.f;
        for (int j = 0; j < 10; j++) se += __expf(vals[j] - mx);
        float lse = logf(se) + mx;
        for (int j = 0; j < 10; j++) out[t * 10 + j] = vals[j] - lse;   // output 0
    }
}

// ---------------- launcher ----------------

extern "C" void kernel_launch(void* const* d_in, const int* in_sizes, int n_in,
                              void* d_out, int out_size, void* d_ws, size_t ws_size,
                              hipStream_t stream)
{
    const float* feat = (const float*)d_in[0];
    const float* Wsrc = (const float*)d_in[1];
    const float* bsrc = (const float*)d_in[2];
    const float* Wdst = (const float*)d_in[3];
    const float* bdst = (const float*)d_in[4];
    const float* attn = (const float*)d_in[5];
    const float* bn_g = (const float*)d_in[6];
    const float* bn_b = (const float*)d_in[7];
    const float* lpW  = (const float*)d_in[8];
    const float* lpb  = (const float*)d_in[9];
    const float* lpg  = (const float*)d_in[10];
    const float* lpbt = (const float*)d_in[11];
    const float* blW  = (const float*)d_in[12];
    const float* blb  = (const float*)d_in[13];
    const float* blg  = (const float*)d_in[14];
    const float* blbt = (const float*)d_in[15];
    const float* llW  = (const float*)d_in[16];
    const float* llb  = (const float*)d_in[17];
    const float* llg  = (const float*)d_in[18];
    const float* llbt = (const float*)d_in[19];
    const int* srcp = (const int*)d_in[20];
    const int* dstp = (const int*)d_in[21];
    const int* gidp = (const int*)d_in[22];
    float* out = (float*)d_out;

    int N = in_sizes[0] / 64;
    int E = in_sizes[20];
    int nb = (N + 1023) / 1024;

    // workspace layout
    float* wsf   = (float*)d_ws;
    float* fs    = wsf;                              // N*256
    float* fd    = fs + (size_t)N * 256;             // N*256
    float* hmean = fd + (size_t)N * 256;             // N*64
    float* pbuf  = hmean + (size_t)N * 64;           // 3*8192
    float* bnA   = pbuf + 3 * 8192;                  // 4*64
    float* bnB   = bnA + 256;                        // 4*64
    float* q     = bnB + 256;                        // 8192
    float* hh    = q + 8192;                         // 8192
    float* zstart = hh + 8192;
    float* bnsum = zstart;                           // 3*64
    float* bnsq  = bnsum + 192;                      // 3*64
    float* qsum  = bnsq + 192;                       // 3*64
    float* qsq   = qsum + 192;                       // 3*64
    float* hsum  = qsq + 192;                        // 64
    float* hsq   = hsum + 64;                        // 64
    float* S     = hsq + 64;                         // 3*8192
    int* deg     = (int*)(S + 3 * 8192);             // N
    int* cursor  = deg + N;                          // N
    int* cntg    = cursor + N;                       // 128
    int* zend    = cntg + 128;
    int* row_ptr = zend;                             // N+1
    int* col_src = row_ptr + (N + 1);                // E
    int* bsum    = col_src + E;                      // nb (<=64)
    int* boff    = bsum + 64;                        // nb (<=64)

    size_t zbytes = (size_t)((char*)zend - (char*)zstart);
    hipMemsetAsync(zstart, 0, zbytes, stream);
    hipLaunchKernelGGL(init_affine_kernel, dim3(1), dim3(64), 0, stream, bnA, bnB);
    hipLaunchKernelGGL(hist_kernel, dim3((E + 255) / 256), dim3(256), 0, stream, dstp, deg, E);
    hipLaunchKernelGGL(cntg_kernel, dim3((N + 255) / 256), dim3(256), 0, stream, gidp, cntg, N);
    hipLaunchKernelGGL(scan_sums_kernel, dim3(nb), dim3(256), 0, stream, deg, bsum, N);
    hipLaunchKernelGGL(scan_offsets_kernel, dim3(1), dim3(64), 0, stream, bsum, boff, row_ptr + N, nb);
    hipLaunchKernelGGL(scan_final_kernel, dim3(nb), dim3(256), 0, stream, deg, boff, row_ptr, N);
    hipLaunchKernelGGL(scatter_kernel, dim3((E + 255) / 256), dim3(256), 0, stream,
                       srcp, dstp, row_ptr, cursor, col_src, E);

    for (int l = 0; l < 3; l++) {
        const float* hsrcp = (l == 0) ? feat : hmean;
        hipLaunchKernelGGL(gemm_kernel, dim3((N + 63) / 64, 8), dim3(256), 0, stream,
                           hsrcp, bnA + l * 64, bnB + l * 64,
                           Wsrc + (size_t)l * 64 * 256, bsrc + l * 256,
                           Wdst + (size_t)l * 64 * 256, bdst + l * 256, fs, fd, N);
        hipLaunchKernelGGL(gat_kernel, dim3((N + 3) / 4), dim3(256), 0, stream,
                           fs, fd, attn + l * 256, row_ptr, col_src, hmean, N);
        hipLaunchKernelGGL(stats_kernel, dim3(128), dim3(256), 0, stream,
                           hmean, gidp, bnsum + l * 64, bnsq + l * 64, S + l * 8192, N);
        hipLaunchKernelGGL(pooled_a_kernel, dim3(128), dim3(256), 0, stream,
                           bnsum + l * 64, bnsq + l * 64, S + l * 8192, cntg,
                           bn_g + l * 64, bn_b + l * 64,
                           lpW + (size_t)l * 64 * 64, lpb + l * 64,
                           q, qsum + l * 64, qsq + l * 64, N);
        hipLaunchKernelGGL(pooled_b_kernel, dim3(1), dim3(256), 0, stream,
                           bnsum + l * 64, bnsq + l * 64, q, qsum + l * 64, qsq + l * 64,
                           bn_g + l * 64, bn_b + l * 64, lpg + l * 64, lpbt + l * 64,
                           bnA + (l + 1) * 64, bnB + (l + 1) * 64, pbuf + l * 8192, N);
    }
    hipLaunchKernelGGL(head_gemm_kernel, dim3(128), dim3(256), 0, stream,
                       pbuf, blW, blb, hh, hsum, hsq);
    hipLaunchKernelGGL(head_finish_kernel, dim3(1), dim3(256), 0, stream,
                       hh, hsum, hsq, blg, blbt, llW, llb, llg, llbt, out);
}

// Round 3
// 823.661 us; speedup vs baseline: 1.6403x; 1.2105x over previous
//
#include <hip/hip_runtime.h>
#include <hip/hip_bf16.h>
#include <cmath>

#define NH 4
#define NG 128

__device__ inline unsigned short f2bf(float f) {
    __hip_bfloat16 h = __float2bfloat16(f);
    return *reinterpret_cast<unsigned short*>(&h);
}

// ---------------- init / CSR build ----------------

__global__ void __launch_bounds__(64) init_affine_kernel(float* bnA, float* bnB) {
    int t = threadIdx.x;
    bnA[t] = 1.f;
    bnB[t] = 0.f;
}

__global__ void __launch_bounds__(256) hist_kernel(const int* __restrict__ dst,
                                                   int* __restrict__ deg, int E) {
    int e = blockIdx.x * 256 + threadIdx.x;
    if (e < E) atomicAdd(&deg[dst[e]], 1);
}

// graph_ids sorted -> boundary positions, no atomics
__global__ void __launch_bounds__(256) bounds_kernel(const int* __restrict__ gid,
                                                     int* __restrict__ start, int N) {
    int n = blockIdx.x * 256 + threadIdx.x;
    if (n >= N) return;
    int a = gid[n];
    if (n == 0)
        for (int g = 0; g <= a; g++) start[g] = 0;
    int b = (n + 1 < N) ? gid[n + 1] : NG;
    for (int g = a + 1; g <= b && g < NG; g++) start[g] = n + 1;
}

__global__ void __launch_bounds__(128) cnt_diff_kernel(const int* __restrict__ start,
                                                       int* __restrict__ cntg, int N) {
    int g = threadIdx.x;
    int s1 = (g == NG - 1) ? N : start[g + 1];
    cntg[g] = s1 - start[g];
}

// 3-phase exclusive scan of deg[N] -> row_ptr[N+1]
__global__ void __launch_bounds__(256) scan_sums_kernel(const int* __restrict__ deg,
                                                        int* __restrict__ bsum, int N) {
    __shared__ int red[256];
    int t = threadIdx.x;
    int base = blockIdx.x * 1024 + t * 4;
    int s = 0;
#pragma unroll
    for (int j = 0; j < 4; j++) { int i = base + j; if (i < N) s += deg[i]; }
    red[t] = s;
    __syncthreads();
    for (int off = 128; off > 0; off >>= 1) {
        if (t < off) red[t] += red[t + off];
        __syncthreads();
    }
    if (t == 0) bsum[blockIdx.x] = red[0];
}

__global__ void scan_offsets_kernel(const int* __restrict__ bsum, int* __restrict__ boff,
                                    int* __restrict__ row_ptr_N, int nb) {
    if (threadIdx.x == 0) {
        int acc = 0;
        for (int b = 0; b < nb; b++) { boff[b] = acc; acc += bsum[b]; }
        row_ptr_N[0] = acc;
    }
}

__global__ void __launch_bounds__(256) scan_final_kernel(const int* __restrict__ deg,
                                                         const int* __restrict__ boff,
                                                         int* __restrict__ row_ptr, int N) {
    __shared__ int red[256];
    int t = threadIdx.x;
    int base = blockIdx.x * 1024 + t * 4;
    int d[4];
    int s = 0;
#pragma unroll
    for (int j = 0; j < 4; j++) {
        int i = base + j;
        d[j] = (i < N) ? deg[i] : 0;
        s += d[j];
    }
    red[t] = s;
    __syncthreads();
    for (int off = 1; off < 256; off <<= 1) {
        int v = (t >= off) ? red[t - off] : 0;
        __syncthreads();
        red[t] += v;
        __syncthreads();
    }
    int excl = red[t] - s + boff[blockIdx.x];
#pragma unroll
    for (int j = 0; j < 4; j++) {
        int i = base + j;
        if (i < N) row_ptr[i] = excl;
        excl += d[j];
    }
}

__global__ void __launch_bounds__(256) scatter_kernel(const int* __restrict__ src,
                                                      const int* __restrict__ dst,
                                                      const int* __restrict__ row_ptr,
                                                      int* __restrict__ cursor,
                                                      int* __restrict__ col_src, int E) {
    int e = blockIdx.x * 256 + threadIdx.x;
    if (e < E) {
        int d = dst[e];
        int pos = row_ptr[d] + atomicAdd(&cursor[d], 1);
        col_src[pos] = src[e];
    }
}

// ---------------- fused BN-affine + dual GEMM: fs(bf16)/fd(fp32) = affine(h) @ W + b ------

__global__ void __launch_bounds__(256) gemm_kernel(
    const float* __restrict__ h, const float* __restrict__ bnA, const float* __restrict__ bnB,
    const float* __restrict__ Wsrc, const float* __restrict__ bsrc,
    const float* __restrict__ Wdst, const float* __restrict__ bdst,
    __hip_bfloat16* __restrict__ fsh, float* __restrict__ fd, int N)
{
    __shared__ __align__(16) float hsT[64][68];
    __shared__ __align__(16) float wt[16][65][4];
    int t = threadIdx.x;
    int row0 = blockIdx.x * 64;
    int yt = blockIdx.y;
    const float* W    = (yt < 4) ? Wsrc : Wdst;
    const float* bias = (yt < 4) ? bsrc : bdst;
    int c0 = (yt & 3) * 64;

#pragma unroll
    for (int i = 0; i < 16; i++) {
        int flat = i * 256 + t;
        int r = flat >> 6, k = flat & 63;
        int gr = row0 + r;
        float v = 0.f;
        if (gr < N) v = h[(size_t)gr * 64 + k] * bnA[k] + bnB[k];
        hsT[k][r] = v;
    }
#pragma unroll
    for (int i = 0; i < 16; i++) {
        int flat = i * 256 + t;
        int k = flat >> 6, c = flat & 63;
        wt[c >> 2][k][c & 3] = W[k * 256 + c0 + c];
    }
    __syncthreads();

    int tc = t & 15, tr = t >> 4;
    float4 bv = *(const float4*)(bias + c0 + 4 * tc);
    float acc[4][4];
#pragma unroll
    for (int i = 0; i < 4; i++) {
        acc[i][0] = bv.x; acc[i][1] = bv.y; acc[i][2] = bv.z; acc[i][3] = bv.w;
    }
#pragma unroll 8
    for (int k = 0; k < 64; k++) {
        float4 a = *(const float4*)&hsT[k][4 * tr];
        float4 b = *(const float4*)&wt[tc][k][0];
        acc[0][0] = fmaf(a.x, b.x, acc[0][0]); acc[0][1] = fmaf(a.x, b.y, acc[0][1]);
        acc[0][2] = fmaf(a.x, b.z, acc[0][2]); acc[0][3] = fmaf(a.x, b.w, acc[0][3]);
        acc[1][0] = fmaf(a.y, b.x, acc[1][0]); acc[1][1] = fmaf(a.y, b.y, acc[1][1]);
        acc[1][2] = fmaf(a.y, b.z, acc[1][2]); acc[1][3] = fmaf(a.y, b.w, acc[1][3]);
        acc[2][0] = fmaf(a.z, b.x, acc[2][0]); acc[2][1] = fmaf(a.z, b.y, acc[2][1]);
        acc[2][2] = fmaf(a.z, b.z, acc[2][2]); acc[2][3] = fmaf(a.z, b.w, acc[2][3]);
        acc[3][0] = fmaf(a.w, b.x, acc[3][0]); acc[3][1] = fmaf(a.w, b.y, acc[3][1]);
        acc[3][2] = fmaf(a.w, b.z, acc[3][2]); acc[3][3] = fmaf(a.w, b.w, acc[3][3]);
    }
    if (yt < 4) {
#pragma unroll
        for (int i = 0; i < 4; i++) {
            int gr = row0 + 4 * tr + i;
            if (gr < N) {
                ushort4 o;
                o.x = f2bf(acc[i][0]); o.y = f2bf(acc[i][1]);
                o.z = f2bf(acc[i][2]); o.w = f2bf(acc[i][3]);
                *(ushort4*)(fsh + (size_t)gr * 256 + c0 + 4 * tc) = o;
            }
        }
    } else {
#pragma unroll
        for (int i = 0; i < 4; i++) {
            int gr = row0 + 4 * tr + i;
            if (gr < N)
                *(float4*)(fd + (size_t)gr * 256 + c0 + 4 * tc) =
                    make_float4(acc[i][0], acc[i][1], acc[i][2], acc[i][3]);
        }
    }
}

// ---------------- fused GATv2 edge phase: one wave per dst node (bf16 fs) ----------------

__global__ void __launch_bounds__(256) gat_kernel(
    const __hip_bfloat16* __restrict__ fsh, const float* __restrict__ fd,
    const float* __restrict__ attn,
    const int* __restrict__ row_ptr, const int* __restrict__ col_src,
    float* __restrict__ hmean, int N)
{
    int wid = (blockIdx.x << 2) + (threadIdx.x >> 6);
    if (wid >= N) return;
    int lane = threadIdx.x & 63;
    int e4 = lane >> 4;
    int dg = lane & 15;
    int rs = row_ptr[wid];
    int deg = row_ptr[wid + 1] - rs;

    float4 att[NH], fdv[NH];
#pragma unroll
    for (int h = 0; h < NH; h++) {
        att[h] = *(const float4*)(attn + h * 64 + dg * 4);
        fdv[h] = *(const float4*)(fd + (size_t)wid * 256 + h * 64 + dg * 4);
    }
    float4 acc[NH];
    float l[NH];
#pragma unroll
    for (int h = 0; h < NH; h++) { acc[h] = make_float4(0.f, 0.f, 0.f, 0.f); l[h] = 0.f; }

    int s_reg = 0;
    if (lane < deg) s_reg = col_src[rs + lane];

    for (int i = 0; i < deg; i += 4) {
        int idx = i + e4;
        bool valid = idx < deg;
        int cidx = valid ? idx : (deg - 1);
        int sh = __shfl(s_reg, min(cidx, 63), 64);
        int s;
        if (cidx < 64) s = sh; else s = col_src[rs + cidx];
        const ushort4* fsp = (const ushort4*)(fsh + (size_t)s * 256);
#pragma unroll
        for (int h = 0; h < NH; h++) {
            ushort4 uv = fsp[h * 16 + dg];
            float vx = __uint_as_float((unsigned)uv.x << 16);
            float vy = __uint_as_float((unsigned)uv.y << 16);
            float vz = __uint_as_float((unsigned)uv.z << 16);
            float vw = __uint_as_float((unsigned)uv.w << 16);
            float x0 = vx + fdv[h].x, x1 = vy + fdv[h].y;
            float x2 = vz + fdv[h].z, x3 = vw + fdv[h].w;
            x0 = fmaxf(x0, 0.2f * x0); x1 = fmaxf(x1, 0.2f * x1);
            x2 = fmaxf(x2, 0.2f * x2); x3 = fmaxf(x3, 0.2f * x3);
            float p = x0 * att[h].x + x1 * att[h].y + x2 * att[h].z + x3 * att[h].w;
            p += __shfl_xor(p, 1); p += __shfl_xor(p, 2);
            p += __shfl_xor(p, 4); p += __shfl_xor(p, 8);
            float e = valid ? __expf(p) : 0.f;
            l[h] += e;
            acc[h].x = fmaf(e, vx, acc[h].x);
            acc[h].y = fmaf(e, vy, acc[h].y);
            acc[h].z = fmaf(e, vz, acc[h].z);
            acc[h].w = fmaf(e, vw, acc[h].w);
        }
    }
#pragma unroll
    for (int h = 0; h < NH; h++) {
#pragma unroll
        for (int off = 16; off <= 32; off <<= 1) {
            l[h] += __shfl_xor(l[h], off);
            acc[h].x += __shfl_xor(acc[h].x, off);
            acc[h].y += __shfl_xor(acc[h].y, off);
            acc[h].z += __shfl_xor(acc[h].z, off);
            acc[h].w += __shfl_xor(acc[h].w, off);
        }
    }
    if (e4 == 0) {
        float4 hm = make_float4(0.f, 0.f, 0.f, 0.f);
#pragma unroll
        for (int h = 0; h < NH; h++) {
            float inv = (l[h] > 0.f) ? 1.f / l[h] : 0.f;
            hm.x += fmaxf(acc[h].x * inv, 0.f);
            hm.y += fmaxf(acc[h].y * inv, 0.f);
            hm.z += fmaxf(acc[h].z * inv, 0.f);
            hm.w += fmaxf(acc[h].w * inv, 0.f);
        }
        hm.x *= 0.25f; hm.y *= 0.25f; hm.z *= 0.25f; hm.w *= 0.25f;
        *(float4*)(hmean + (size_t)wid * 64 + dg * 4) = hm;
    }
}

// ---------------- BN stats + graph segment sums (raw hmean) ----------------

__global__ void __launch_bounds__(256) stats_kernel(
    const float* __restrict__ hmean, const int* __restrict__ gid,
    float* __restrict__ bnsum, float* __restrict__ bnsumsq,
    float* __restrict__ S, int N)
{
    __shared__ float bs[4][64], bq[4][64];
    int t = threadIdx.x, lane = t & 63, w = t >> 6;
    int wglobal = blockIdx.x * 4 + w;
    int chunk = (N + 511) >> 9;
    int n0 = wglobal * chunk;
    int n1 = min(n0 + chunk, N);
    float sum = 0.f, sq = 0.f, run = 0.f;
    int cur = -1;
    for (int n = n0; n < n1; n++) {
        float v = hmean[(size_t)n * 64 + lane];
        int g = gid[n];
        if (g != cur) {
            if (cur >= 0) atomicAdd(&S[cur * 64 + lane], run);
            run = 0.f;
            cur = g;
        }
        run += v;
        sum += v;
        sq = fmaf(v, v, sq);
    }
    if (cur >= 0) atomicAdd(&S[cur * 64 + lane], run);
    bs[w][lane] = sum;
    bq[w][lane] = sq;
    __syncthreads();
    if (w == 0) {
        float s2 = bs[0][lane] + bs[1][lane] + bs[2][lane] + bs[3][lane];
        float q2 = bq[0][lane] + bq[1][lane] + bq[2][lane] + bq[3][lane];
        atomicAdd(&bnsum[lane], s2);
        atomicAdd(&bnsumsq[lane], q2);
    }
}

// ---------------- pooled path A: per-graph MLP row (128 blocks) ----------------

__global__ void __launch_bounds__(256) pooled_a_kernel(
    const float* __restrict__ bnsum, const float* __restrict__ bnsumsq,
    const float* __restrict__ S, const int* __restrict__ cntg,
    const float* __restrict__ bn_g, const float* __restrict__ bn_b,
    const float* __restrict__ lpW, const float* __restrict__ lpb,
    float* __restrict__ q, float* __restrict__ qsum, float* __restrict__ qsq, int N)
{
    __shared__ float sv[64];
    __shared__ float partial[4][64];
    int g = blockIdx.x;
    int t = threadIdx.x;
    if (t < 64) {
        float mu = bnsum[t] / (float)N;
        float var = bnsumsq[t] / (float)N - mu * mu;
        float a = bn_g[t] / sqrtf(var + 1e-5f);
        float b = bn_b[t] - mu * a;
        sv[t] = a * S[g * 64 + t] + b * (float)cntg[g];
    }
    __syncthreads();
    int f = t & 63, kc = t >> 6;
    float acc = 0.f;
#pragma unroll
    for (int k = kc * 16; k < kc * 16 + 16; k++)
        acc = fmaf(sv[k], lpW[k * 64 + f], acc);
    partial[kc][f] = acc;
    __syncthreads();
    if (t < 64) {
        float v = partial[0][t] + partial[1][t] + partial[2][t] + partial[3][t] + lpb[t];
        v = fmaxf(v, 0.f);
        q[g * 64 + t] = v;
        atomicAdd(&qsum[t], v);
        atomicAdd(&qsq[t], v * v);
    }
}

// ---------------- pooled path B: BN over graphs + next-layer node-BN affine ----------------

__global__ void __launch_bounds__(256) pooled_b_kernel(
    const float* __restrict__ bnsum, const float* __restrict__ bnsumsq,
    const float* __restrict__ q, const float* __restrict__ qsum, const float* __restrict__ qsq,
    const float* __restrict__ bn_g, const float* __restrict__ bn_b,
    const float* __restrict__ lpg, const float* __restrict__ lpbt,
    float* __restrict__ bnA_out, float* __restrict__ bnB_out,
    float* __restrict__ p_out, int N)
{
    __shared__ float mu2[64], sc2[64];
    int t = threadIdx.x;
    if (t < 64) {
        float mu = bnsum[t] / (float)N;
        float var = bnsumsq[t] / (float)N - mu * mu;
        float a = bn_g[t] / sqrtf(var + 1e-5f);
        bnA_out[t] = a;
        bnB_out[t] = bn_b[t] - mu * a;
        float m = qsum[t] * (1.f / 128.f);
        float v = qsq[t] * (1.f / 128.f) - m * m;
        mu2[t] = m;
        sc2[t] = lpg[t] / sqrtf(v + 1e-5f);
    }
    __syncthreads();
    for (int i = t; i < 128 * 64; i += 256) {
        int ff = i & 63;
        p_out[i] = (q[i] - mu2[ff]) * sc2[ff] + lpbt[ff];
    }
}

// ---------------- head A: hh = relu(cat @ blW + blb), 128 blocks, stats atomics ----------------

__global__ void __launch_bounds__(256) head_gemm_kernel(
    const float* __restrict__ p, const float* __restrict__ blW, const float* __restrict__ blb,
    float* __restrict__ hh, float* __restrict__ hsum, float* __restrict__ hsq)
{
    __shared__ float cat[192];
    __shared__ float partial[4][64];
    int g = blockIdx.x;
    int t = threadIdx.x;
    if (t < 192) cat[t] = p[(t >> 6) * 8192 + g * 64 + (t & 63)];
    __syncthreads();
    int f = t & 63, kc = t >> 6;
    float acc = 0.f;
#pragma unroll
    for (int k = kc * 48; k < kc * 48 + 48; k++)
        acc = fmaf(cat[k], blW[k * 64 + f], acc);
    partial[kc][f] = acc;
    __syncthreads();
    if (t < 64) {
        float v = partial[0][t] + partial[1][t] + partial[2][t] + partial[3][t] + blb[t];
        v = fmaxf(v, 0.f);
        hh[g * 64 + t] = v;
        atomicAdd(&hsum[t], v);
        atomicAdd(&hsq[t], v * v);
    }
}

// ---------------- head B: BN, second linear, BN, log_softmax ----------------

__global__ void __launch_bounds__(256) head_finish_kernel(
    const float* __restrict__ hh, const float* __restrict__ hsum, const float* __restrict__ hsq,
    const float* __restrict__ blg, const float* __restrict__ blbt,
    const float* __restrict__ llW, const float* __restrict__ llb,
    const float* __restrict__ llg, const float* __restrict__ llbt,
    float* __restrict__ out)
{
    __shared__ float hn[128][65];
    __shared__ float ph[128][12];
    __shared__ float mu[64], sc[64];
    __shared__ float mj[12], scj[12];
    __shared__ float sW[640];
    int t = threadIdx.x;
    if (t < 64) {
        float m = hsum[t] * (1.f / 128.f);
        float v = hsq[t] * (1.f / 128.f) - m * m;
        mu[t] = m;
        sc[t] = blg[t] / sqrtf(v + 1e-5f);
    }
    for (int i = t; i < 640; i += 256) sW[i] = llW[i];
    __syncthreads();
    for (int i = t; i < 8192; i += 256) {
        int g = i >> 6, ff = i & 63;
        float v = (hh[i] - mu[ff]) * sc[ff] + blbt[ff];
        out[1280 + i] = v;          // output 1: pooled_hh
        hn[g][ff] = v;
    }
    __syncthreads();
    for (int i = t; i < 1280; i += 256) {
        int g = i / 10, j = i - g * 10;
        float s = llb[j];
#pragma unroll 8
        for (int k = 0; k < 64; k++) s = fmaf(hn[g][k], sW[k * 10 + j], s);
        ph[g][j] = fmaxf(s, 0.f);
    }
    __syncthreads();
    if (t < 10) {
        float m = 0.f;
        for (int g = 0; g < 128; g++) m += ph[g][t];
        m *= (1.f / 128.f);
        float v = 0.f;
        for (int g = 0; g < 128; g++) { float d = ph[g][t] - m; v = fmaf(d, d, v); }
        v *= (1.f / 128.f);
        mj[t] = m;
        scj[t] = llg[t] / sqrtf(v + 1e-5f);
    }
    __syncthreads();
    if (t < 128) {
        float vals[10];
        float mx = -1e30f;
        for (int j = 0; j < 10; j++) {
            vals[j] = (ph[t][j] - mj[j]) * scj[j] + llbt[j];
            mx = fmaxf(mx, vals[j]);
        }
        float se = 0.f;
        for (int j = 0; j < 10; j++) se += __expf(vals[j] - mx);
        float lse = logf(se) + mx;
        for (int j = 0; j < 10; j++) out[t * 10 + j] = vals[j] - lse;   // output 0
    }
}

// ---------------- launcher ----------------

extern "C" void kernel_launch(void* const* d_in, const int* in_sizes, int n_in,
                              void* d_out, int out_size, void* d_ws, size_t ws_size,
                              hipStream_t stream)
{
    const float* feat = (const float*)d_in[0];
    const float* Wsrc = (const float*)d_in[1];
    const float* bsrc = (const float*)d_in[2];
    const float* Wdst = (const float*)d_in[3];
    const float* bdst = (const float*)d_in[4];
    const float* attn = (const float*)d_in[5];
    const float* bn_g = (const float*)d_in[6];
    const float* bn_b = (const float*)d_in[7];
    const float* lpW  = (const float*)d_in[8];
    const float* lpb  = (const float*)d_in[9];
    const float* lpg  = (const float*)d_in[10];
    const float* lpbt = (const float*)d_in[11];
    const float* blW  = (const float*)d_in[12];
    const float* blb  = (const float*)d_in[13];
    const float* blg  = (const float*)d_in[14];
    const float* blbt = (const float*)d_in[15];
    const float* llW  = (const float*)d_in[16];
    const float* llb  = (const float*)d_in[17];
    const float* llg  = (const float*)d_in[18];
    const float* llbt = (const float*)d_in[19];
    const int* srcp = (const int*)d_in[20];
    const int* dstp = (const int*)d_in[21];
    const int* gidp = (const int*)d_in[22];
    float* out = (float*)d_out;

    int N = in_sizes[0] / 64;
    int E = in_sizes[20];
    int nb = (N + 1023) / 1024;

    // workspace layout
    float* wsf   = (float*)d_ws;
    __hip_bfloat16* fsh = (__hip_bfloat16*)wsf;      // N*256 bf16 = N*128 floats
    float* fd    = wsf + (size_t)N * 128;            // N*256
    float* hmean = fd + (size_t)N * 256;             // N*64
    float* pbuf  = hmean + (size_t)N * 64;           // 3*8192
    float* bnA   = pbuf + 3 * 8192;                  // 4*64
    float* bnB   = bnA + 256;                        // 4*64
    float* q     = bnB + 256;                        // 8192
    float* hh    = q + 8192;                         // 8192
    float* zstart = hh + 8192;
    float* bnsum = zstart;                           // 3*64
    float* bnsq  = bnsum + 192;                      // 3*64
    float* qsum  = bnsq + 192;                       // 3*64
    float* qsq   = qsum + 192;                       // 3*64
    float* hsum  = qsq + 192;                        // 64
    float* hsq   = hsum + 64;                        // 64
    float* S     = hsq + 64;                         // 3*8192
    int* deg     = (int*)(S + 3 * 8192);             // N
    int* cursor  = deg + N;                          // N
    int* zend    = cursor + N;
    int* cntg    = zend;                             // 128
    int* gstart  = cntg + 128;                       // 128
    int* row_ptr = gstart + 128;                     // N+1
    int* col_src = row_ptr + (N + 1);                // E
    int* bsum    = col_src + E;                      // nb (<=64)
    int* boff    = bsum + 64;                        // nb (<=64)

    size_t zbytes = (size_t)((char*)zend - (char*)zstart);
    hipMemsetAsync(zstart, 0, zbytes, stream);
    hipLaunchKernelGGL(init_affine_kernel, dim3(1), dim3(64), 0, stream, bnA, bnB);
    hipLaunchKernelGGL(hist_kernel, dim3((E + 255) / 256), dim3(256), 0, stream, dstp, deg, E);
    hipLaunchKernelGGL(bounds_kernel, dim3((N + 255) / 256), dim3(256), 0, stream, gidp, gstart, N);
    hipLaunchKernelGGL(cnt_diff_kernel, dim3(1), dim3(128), 0, stream, gstart, cntg, N);
    hipLaunchKernelGGL(scan_sums_kernel, dim3(nb), dim3(256), 0, stream, deg, bsum, N);
    hipLaunchKernelGGL(scan_offsets_kernel, dim3(1), dim3(64), 0, stream, bsum, boff, row_ptr + N, nb);
    hipLaunchKernelGGL(scan_final_kernel, dim3(nb), dim3(256), 0, stream, deg, boff, row_ptr, N);
    hipLaunchKernelGGL(scatter_kernel, dim3((E + 255) / 256), dim3(256), 0, stream,
                       srcp, dstp, row_ptr, cursor, col_src, E);

    for (int l = 0; l < 3; l++) {
        const float* hsrcp = (l == 0) ? feat : hmean;
        hipLaunchKernelGGL(gemm_kernel, dim3((N + 63) / 64, 8), dim3(256), 0, stream,
                           hsrcp, bnA + l * 64, bnB + l * 64,
                           Wsrc + (size_t)l * 64 * 256, bsrc + l * 256,
                           Wdst + (size_t)l * 64 * 256, bdst + l * 256, fsh, fd, N);
        hipLaunchKernelGGL(gat_kernel, dim3((N + 3) / 4), dim3(256), 0, stream,
                           fsh, fd, attn + l * 256, row_ptr, col_src, hmean, N);
        hipLaunchKernelGGL(stats_kernel, dim3(128), dim3(256), 0, stream,
                           hmean, gidp, bnsum + l * 64, bnsq + l * 64, S + l * 8192, N);
        hipLaunchKernelGGL(pooled_a_kernel, dim3(128), dim3(256), 0, stream,
                           bnsum + l * 64, bnsq + l * 64, S + l * 8192, cntg,
                           bn_g + l * 64, bn_b + l * 64,
                           lpW + (size_t)l * 64 * 64, lpb + l * 64,
                           q, qsum + l * 64, qsq + l * 64, N);
        hipLaunchKernelGGL(pooled_b_kernel, dim3(1), dim3(256), 0, stream,
                           bnsum + l * 64, bnsq + l * 64, q, qsum + l * 64, qsq + l * 64,
                           bn_g + l * 64, bn_b + l * 64, lpg + l * 64, lpbt + l * 64,
                           bnA + (l + 1) * 64, bnB + (l + 1) * 64, pbuf + l * 8192, N);
    }
    hipLaunchKernelGGL(head_gemm_kernel, dim3(128), dim3(256), 0, stream,
                       pbuf, blW, blb, hh, hsum, hsq);
    hipLaunchKernelGGL(head_finish_kernel, dim3(1), dim3(256), 0, stream,
                       hh, hsum, hsq, blg, blbt, llW, llb, llg, llbt, out);
}

// Round 4
// 609.021 us; speedup vs baseline: 2.2185x; 1.3524x over previous
//
#include <hip/hip_runtime.h>
#include <cmath>

#define NH 4
#define NG 128

typedef _Float16 half8 __attribute__((ext_vector_type(8)));
typedef _Float16 half2v __attribute__((ext_vector_type(2)));
typedef float f32x4 __attribute__((ext_vector_type(4)));

#if defined(__has_builtin)
# if __has_builtin(__builtin_amdgcn_fdot2)
#  define USE_FDOT2 1
# endif
#endif

// ---------------- init / CSR build ----------------

__global__ void __launch_bounds__(64) init_affine_kernel(float* bnA, float* bnB) {
    int t = threadIdx.x;
    bnA[t] = 1.f;
    bnB[t] = 0.f;
}

__global__ void __launch_bounds__(256) hist_kernel(const int* __restrict__ dst,
                                                   int* __restrict__ deg, int E) {
    int e = blockIdx.x * 256 + threadIdx.x;
    if (e < E) atomicAdd(&deg[dst[e]], 1);
}

// graph_ids sorted -> boundary positions, no atomics
__global__ void __launch_bounds__(256) bounds_kernel(const int* __restrict__ gid,
                                                     int* __restrict__ start, int N) {
    int n = blockIdx.x * 256 + threadIdx.x;
    if (n >= N) return;
    int a = gid[n];
    if (n == 0)
        for (int g = 0; g <= a; g++) start[g] = 0;
    int b = (n + 1 < N) ? gid[n + 1] : NG;
    for (int g = a + 1; g <= b && g < NG; g++) start[g] = n + 1;
}

__global__ void __launch_bounds__(128) cnt_diff_kernel(const int* __restrict__ start,
                                                       int* __restrict__ cntg, int N) {
    int g = threadIdx.x;
    int s1 = (g == NG - 1) ? N : start[g + 1];
    cntg[g] = s1 - start[g];
}

// 3-phase exclusive scan of deg[N] -> row_ptr[N+1]
__global__ void __launch_bounds__(256) scan_sums_kernel(const int* __restrict__ deg,
                                                        int* __restrict__ bsum, int N) {
    __shared__ int red[256];
    int t = threadIdx.x;
    int base = blockIdx.x * 1024 + t * 4;
    int s = 0;
#pragma unroll
    for (int j = 0; j < 4; j++) { int i = base + j; if (i < N) s += deg[i]; }
    red[t] = s;
    __syncthreads();
    for (int off = 128; off > 0; off >>= 1) {
        if (t < off) red[t] += red[t + off];
        __syncthreads();
    }
    if (t == 0) bsum[blockIdx.x] = red[0];
}

__global__ void scan_offsets_kernel(const int* __restrict__ bsum, int* __restrict__ boff,
                                    int* __restrict__ row_ptr_N, int nb) {
    if (threadIdx.x == 0) {
        int acc = 0;
        for (int b = 0; b < nb; b++) { boff[b] = acc; acc += bsum[b]; }
        row_ptr_N[0] = acc;
    }
}

__global__ void __launch_bounds__(256) scan_final_kernel(const int* __restrict__ deg,
                                                         const int* __restrict__ boff,
                                                         int* __restrict__ row_ptr, int N) {
    __shared__ int red[256];
    int t = threadIdx.x;
    int base = blockIdx.x * 1024 + t * 4;
    int d[4];
    int s = 0;
#pragma unroll
    for (int j = 0; j < 4; j++) {
        int i = base + j;
        d[j] = (i < N) ? deg[i] : 0;
        s += d[j];
    }
    red[t] = s;
    __syncthreads();
    for (int off = 1; off < 256; off <<= 1) {
        int v = (t >= off) ? red[t - off] : 0;
        __syncthreads();
        red[t] += v;
        __syncthreads();
    }
    int excl = red[t] - s + boff[blockIdx.x];
#pragma unroll
    for (int j = 0; j < 4; j++) {
        int i = base + j;
        if (i < N) row_ptr[i] = excl;
        excl += d[j];
    }
}

__global__ void __launch_bounds__(256) scatter_kernel(const int* __restrict__ src,
                                                      const int* __restrict__ dst,
                                                      const int* __restrict__ row_ptr,
                                                      int* __restrict__ cursor,
                                                      int* __restrict__ col_src, int E) {
    int e = blockIdx.x * 256 + threadIdx.x;
    if (e < E) {
        int d = dst[e];
        int pos = row_ptr[d] + atomicAdd(&cursor[d], 1);
        col_src[pos] = src[e];
    }
}

// ---------------- fused BN-affine + dual GEMM via f16 MFMA ----------------
// grid (ceil(N/64), 2): y=0 -> fs, y=1 -> fd. Block 256 = 4 waves.
// Block computes 64 rows x 256 cols, K=64. Wave w owns cols [w*64, w*64+64).
// As[m][k] f16 (rows padded to 72), Bt[c][k] f16 (padded 72) -> b128 frag reads.

__global__ void __launch_bounds__(256) gemm_kernel(
    const float* __restrict__ h, const float* __restrict__ bnA, const float* __restrict__ bnB,
    const float* __restrict__ Wsrc, const float* __restrict__ bsrc,
    const float* __restrict__ Wdst, const float* __restrict__ bdst,
    _Float16* __restrict__ fsh, _Float16* __restrict__ fdh, int N)
{
    __shared__ _Float16 As[64 * 72];
    __shared__ _Float16 Bt[256 * 72];
    int t = threadIdx.x;
    int row0 = blockIdx.x * 64;
    const float* W    = blockIdx.y ? Wdst : Wsrc;
    const float* bias = blockIdx.y ? bdst : bsrc;
    _Float16* out     = blockIdx.y ? fdh : fsh;

    // stage A: affine(h) -> f16, [m][k], k contiguous
#pragma unroll
    for (int i = 0; i < 16; i++) {
        int flat = i * 256 + t;
        int r = flat >> 6, k = flat & 63;
        int gr = row0 + r;
        float v = (gr < N) ? h[(size_t)gr * 64 + k] * bnA[k] + bnB[k] : 0.f;
        As[r * 72 + k] = (_Float16)v;
    }
    // stage B transposed: thread t owns col c=t; per k coalesced global reads
    {
        int c = t;
#pragma unroll
        for (int k0 = 0; k0 < 64; k0 += 8) {
            half8 pk;
#pragma unroll
            for (int j = 0; j < 8; j++) pk[j] = (_Float16)W[(k0 + j) * 256 + c];
            *(half8*)(&Bt[c * 72 + k0]) = pk;
        }
    }
    __syncthreads();

    int w = t >> 6, lane = t & 63;
    int n16 = lane & 15, q = lane >> 4;
    int cw = w * 64;
    f32x4 acc[4][4];
#pragma unroll
    for (int mt = 0; mt < 4; mt++)
#pragma unroll
        for (int nt = 0; nt < 4; nt++) acc[mt][nt] = (f32x4)(0.f);
    float bv[4];
#pragma unroll
    for (int nt = 0; nt < 4; nt++) bv[nt] = bias[cw + nt * 16 + n16];

#pragma unroll
    for (int kk = 0; kk < 2; kk++) {
        half8 af[4], bf[4];
#pragma unroll
        for (int mt = 0; mt < 4; mt++)
            af[mt] = *(const half8*)(&As[(mt * 16 + n16) * 72 + kk * 32 + q * 8]);
#pragma unroll
        for (int nt = 0; nt < 4; nt++)
            bf[nt] = *(const half8*)(&Bt[(cw + nt * 16 + n16) * 72 + kk * 32 + q * 8]);
#pragma unroll
        for (int mt = 0; mt < 4; mt++)
#pragma unroll
            for (int nt = 0; nt < 4; nt++)
                acc[mt][nt] = __builtin_amdgcn_mfma_f32_16x16x32_f16(af[mt], bf[nt], acc[mt][nt], 0, 0, 0);
    }
    // epilogue: C/D layout col=lane&15, row=q*4+reg
#pragma unroll
    for (int mt = 0; mt < 4; mt++) {
#pragma unroll
        for (int i = 0; i < 4; i++) {
            int gr = row0 + mt * 16 + q * 4 + i;
            if (gr < N) {
#pragma unroll
                for (int nt = 0; nt < 4; nt++)
                    out[(size_t)gr * 256 + cw + nt * 16 + n16] = (_Float16)(acc[mt][nt][i] + bv[nt]);
            }
        }
    }
}

// ---------------- fused GATv2 edge phase: one wave per dst node (f16 packed) --------------
// lane = e2*32 + d8: e2 = edge slot (2 edges/pair), d8 = 8-dim group (16 B per lane).
// 4 edges per iter (2 pairs). Packed f16 add/leaky, fdot2 logits (fp32), fma_mix msg acc.

__global__ void __launch_bounds__(256) gat_kernel(
    const _Float16* __restrict__ fsh, const _Float16* __restrict__ fdh,
    const float* __restrict__ attn,
    const int* __restrict__ row_ptr, const int* __restrict__ col_src,
    float* __restrict__ hmean, int N)
{
    int wid = (blockIdx.x << 2) + (threadIdx.x >> 6);
    if (wid >= N) return;
    int lane = threadIdx.x & 63;
    int e2 = lane >> 5;
    int d8 = lane & 31;
    int rs = row_ptr[wid];
    int deg = row_ptr[wid + 1] - rs;

    half8 fdv = *(const half8*)(fdh + (size_t)wid * 256 + d8 * 8);
    const float* ap = attn + (d8 >> 3) * 64 + (d8 & 7) * 8;
    half8 att;
#pragma unroll
    for (int j = 0; j < 8; j++) att[j] = (_Float16)ap[j];
    half8 k02;
#pragma unroll
    for (int j = 0; j < 8; j++) k02[j] = (_Float16)0.2f;

    float acc[8];
#pragma unroll
    for (int j = 0; j < 8; j++) acc[j] = 0.f;
    float l = 0.f;

    int s_reg = 0;
    if (lane < deg) s_reg = col_src[rs + lane];

    for (int i = 0; i < deg; i += 4) {
        int idx0 = i + e2, idx1 = i + 2 + e2;
        bool v0 = idx0 < deg, v1 = idx1 < deg;
        int c0 = v0 ? idx0 : 0;
        int c1 = v1 ? idx1 : 0;
        int s0 = (c0 < 64) ? __shfl(s_reg, c0, 64) : col_src[rs + c0];
        int s1 = (c1 < 64) ? __shfl(s_reg, c1, 64) : col_src[rs + c1];
        half8 f0 = *(const half8*)(fsh + (size_t)s0 * 256 + d8 * 8);
        half8 f1 = *(const half8*)(fsh + (size_t)s1 * 256 + d8 * 8);
#pragma unroll
        for (int u = 0; u < 2; u++) {
            half8 fv = u ? f1 : f0;
            bool valid = u ? v1 : v0;
            half8 x = fv + fdv;
            half8 lx = __builtin_elementwise_max(x, x * k02);
            float p = 0.f;
#ifdef USE_FDOT2
#pragma unroll
            for (int j = 0; j < 4; j++) {
                half2v a2 = { lx[2 * j], lx[2 * j + 1] };
                half2v b2 = { att[2 * j], att[2 * j + 1] };
                p = __builtin_amdgcn_fdot2(a2, b2, p, false);
            }
#else
#pragma unroll
            for (int j = 0; j < 8; j++) p = fmaf((float)lx[j], (float)att[j], p);
#endif
            p += __shfl_xor(p, 1); p += __shfl_xor(p, 2); p += __shfl_xor(p, 4);
            float e = valid ? __expf(p) : 0.f;
            l += e;
#pragma unroll
            for (int j = 0; j < 8; j++) acc[j] = fmaf(e, (float)fv[j], acc[j]);
        }
    }
    // combine the two edge-slot halves
    l += __shfl_xor(l, 32);
#pragma unroll
    for (int j = 0; j < 8; j++) acc[j] += __shfl_xor(acc[j], 32);

    float inv = (l > 0.f) ? 0.25f / l : 0.f;   // fold head-mean (relu(c*x)=c*relu(x), c>0)
    float m[8];
#pragma unroll
    for (int j = 0; j < 8; j++) m[j] = fmaxf(acc[j] * inv, 0.f);
    // cross-head sum: lanes d8, d8^8, d8^16 (same dim-in-head, 4 heads)
#pragma unroll
    for (int j = 0; j < 8; j++) {
        m[j] += __shfl_xor(m[j], 8);
        m[j] += __shfl_xor(m[j], 16);
    }
    if (lane < 8) {
        float4 o0 = make_float4(m[0], m[1], m[2], m[3]);
        float4 o1 = make_float4(m[4], m[5], m[6], m[7]);
        *(float4*)(hmean + (size_t)wid * 64 + d8 * 8) = o0;
        *(float4*)(hmean + (size_t)wid * 64 + d8 * 8 + 4) = o1;
    }
}

// ---------------- BN stats + graph segment sums (raw hmean) ----------------

__global__ void __launch_bounds__(256) stats_kernel(
    const float* __restrict__ hmean, const int* __restrict__ gid,
    float* __restrict__ bnsum, float* __restrict__ bnsumsq,
    float* __restrict__ S, int N)
{
    __shared__ float bs[4][64], bq[4][64];
    int t = threadIdx.x, lane = t & 63, w = t >> 6;
    int wglobal = blockIdx.x * 4 + w;
    int chunk = (N + 511) >> 9;
    int n0 = wglobal * chunk;
    int n1 = min(n0 + chunk, N);
    float sum = 0.f, sq = 0.f, run = 0.f;
    int cur = -1;
    for (int n = n0; n < n1; n++) {
        float v = hmean[(size_t)n * 64 + lane];
        int g = gid[n];
        if (g != cur) {
            if (cur >= 0) atomicAdd(&S[cur * 64 + lane], run);
            run = 0.f;
            cur = g;
        }
        run += v;
        sum += v;
        sq = fmaf(v, v, sq);
    }
    if (cur >= 0) atomicAdd(&S[cur * 64 + lane], run);
    bs[w][lane] = sum;
    bq[w][lane] = sq;
    __syncthreads();
    if (w == 0) {
        float s2 = bs[0][lane] + bs[1][lane] + bs[2][lane] + bs[3][lane];
        float q2 = bq[0][lane] + bq[1][lane] + bq[2][lane] + bq[3][lane];
        atomicAdd(&bnsum[lane], s2);
        atomicAdd(&bnsumsq[lane], q2);
    }
}

// ---------------- pooled path A: per-graph MLP row (128 blocks) ----------------

__global__ void __launch_bounds__(256) pooled_a_kernel(
    const float* __restrict__ bnsum, const float* __restrict__ bnsumsq,
    const float* __restrict__ S, const int* __restrict__ cntg,
    const float* __restrict__ bn_g, const float* __restrict__ bn_b,
    const float* __restrict__ lpW, const float* __restrict__ lpb,
    float* __restrict__ q, float* __restrict__ qsum, float* __restrict__ qsq, int N)
{
    __shared__ float sv[64];
    __shared__ float partial[4][64];
    int g = blockIdx.x;
    int t = threadIdx.x;
    if (t < 64) {
        float mu = bnsum[t] / (float)N;
        float var = bnsumsq[t] / (float)N - mu * mu;
        float a = bn_g[t] / sqrtf(var + 1e-5f);
        float b = bn_b[t] - mu * a;
        sv[t] = a * S[g * 64 + t] + b * (float)cntg[g];
    }
    __syncthreads();
    int f = t & 63, kc = t >> 6;
    float acc = 0.f;
#pragma unroll
    for (int k = kc * 16; k < kc * 16 + 16; k++)
        acc = fmaf(sv[k], lpW[k * 64 + f], acc);
    partial[kc][f] = acc;
    __syncthreads();
    if (t < 64) {
        float v = partial[0][t] + partial[1][t] + partial[2][t] + partial[3][t] + lpb[t];
        v = fmaxf(v, 0.f);
        q[g * 64 + t] = v;
        atomicAdd(&qsum[t], v);
        atomicAdd(&qsq[t], v * v);
    }
}

// ---------------- pooled path B: BN over graphs + next-layer node-BN affine ----------------

__global__ void __launch_bounds__(256) pooled_b_kernel(
    const float* __restrict__ bnsum, const float* __restrict__ bnsumsq,
    const float* __restrict__ q, const float* __restrict__ qsum, const float* __restrict__ qsq,
    const float* __restrict__ bn_g, const float* __restrict__ bn_b,
    const float* __restrict__ lpg, const float* __restrict__ lpbt,
    float* __restrict__ bnA_out, float* __restrict__ bnB_out,
    float* __restrict__ p_out, int N)
{
    __shared__ float mu2[64], sc2[64];
    int t = threadIdx.x;
    if (t < 64) {
        float mu = bnsum[t] / (float)N;
        float var = bnsumsq[t] / (float)N - mu * mu;
        float a = bn_g[t] / sqrtf(var + 1e-5f);
        bnA_out[t] = a;
        bnB_out[t] = bn_b[t] - mu * a;
        float m = qsum[t] * (1.f / 128.f);
        float v = qsq[t] * (1.f / 128.f) - m * m;
        mu2[t] = m;
        sc2[t] = lpg[t] / sqrtf(v + 1e-5f);
    }
    __syncthreads();
    for (int i = t; i < 128 * 64; i += 256) {
        int ff = i & 63;
        p_out[i] = (q[i] - mu2[ff]) * sc2[ff] + lpbt[ff];
    }
}

// ---------------- head A: hh = relu(cat @ blW + blb), 128 blocks, stats atomics ----------------

__global__ void __launch_bounds__(256) head_gemm_kernel(
    const float* __restrict__ p, const float* __restrict__ blW, const float* __restrict__ blb,
    float* __restrict__ hh, float* __restrict__ hsum, float* __restrict__ hsq)
{
    __shared__ float cat[192];
    __shared__ float partial[4][64];
    int g = blockIdx.x;
    int t = threadIdx.x;
    if (t < 192) cat[t] = p[(t >> 6) * 8192 + g * 64 + (t & 63)];
    __syncthreads();
    int f = t & 63, kc = t >> 6;
    float acc = 0.f;
#pragma unroll
    for (int k = kc * 48; k < kc * 48 + 48; k++)
        acc = fmaf(cat[k], blW[k * 64 + f], acc);
    partial[kc][f] = acc;
    __syncthreads();
    if (t < 64) {
        float v = partial[0][t] + partial[1][t] + partial[2][t] + partial[3][t] + blb[t];
        v = fmaxf(v, 0.f);
        hh[g * 64 + t] = v;
        atomicAdd(&hsum[t], v);
        atomicAdd(&hsq[t], v * v);
    }
}

// ---------------- head B: BN, second linear, BN, log_softmax ----------------

__global__ void __launch_bounds__(256) head_finish_kernel(
    const float* __restrict__ hh, const float* __restrict__ hsum, const float* __restrict__ hsq,
    const float* __restrict__ blg, const float* __restrict__ blbt,
    const float* __restrict__ llW, const float* __restrict__ llb,
    const float* __restrict__ llg, const float* __restrict__ llbt,
    float* __restrict__ out)
{
    __shared__ float hn[128][65];
    __shared__ float ph[128][12];
    __shared__ float mu[64], sc[64];
    __shared__ float mj[12], scj[12];
    __shared__ float sW[640];
    int t = threadIdx.x;
    if (t < 64) {
        float m = hsum[t] * (1.f / 128.f);
        float v = hsq[t] * (1.f / 128.f) - m * m;
        mu[t] = m;
        sc[t] = blg[t] / sqrtf(v + 1e-5f);
    }
    for (int i = t; i < 640; i += 256) sW[i] = llW[i];
    __syncthreads();
    for (int i = t; i < 8192; i += 256) {
        int g = i >> 6, ff = i & 63;
        float v = (hh[i] - mu[ff]) * sc[ff] + blbt[ff];
        out[1280 + i] = v;          // output 1: pooled_hh
        hn[g][ff] = v;
    }
    __syncthreads();
    for (int i = t; i < 1280; i += 256) {
        int g = i / 10, j = i - g * 10;
        float s = llb[j];
#pragma unroll 8
        for (int k = 0; k < 64; k++) s = fmaf(hn[g][k], sW[k * 10 + j], s);
        ph[g][j] = fmaxf(s, 0.f);
    }
    __syncthreads();
    if (t < 10) {
        float m = 0.f;
        for (int g = 0; g < 128; g++) m += ph[g][t];
        m *= (1.f / 128.f);
        float v = 0.f;
        for (int g = 0; g < 128; g++) { float d = ph[g][t] - m; v = fmaf(d, d, v); }
        v *= (1.f / 128.f);
        mj[t] = m;
        scj[t] = llg[t] / sqrtf(v + 1e-5f);
    }
    __syncthreads();
    if (t < 128) {
        float vals[10];
        float mx = -1e30f;
        for (int j = 0; j < 10; j++) {
            vals[j] = (ph[t][j] - mj[j]) * scj[j] + llbt[j];
            mx = fmaxf(mx, vals[j]);
        }
        float se = 0.f;
        for (int j = 0; j < 10; j++) se += __expf(vals[j] - mx);
        float lse = logf(se) + mx;
        for (int j = 0; j < 10; j++) out[t * 10 + j] = vals[j] - lse;   // output 0
    }
}

// ---------------- launcher ----------------

extern "C" void kernel_launch(void* const* d_in, const int* in_sizes, int n_in,
                              void* d_out, int out_size, void* d_ws, size_t ws_size,
                              hipStream_t stream)
{
    const float* feat = (const float*)d_in[0];
    const float* Wsrc = (const float*)d_in[1];
    const float* bsrc = (const float*)d_in[2];
    const float* Wdst = (const float*)d_in[3];
    const float* bdst = (const float*)d_in[4];
    const float* attn = (const float*)d_in[5];
    const float* bn_g = (const float*)d_in[6];
    const float* bn_b = (const float*)d_in[7];
    const float* lpW  = (const float*)d_in[8];
    const float* lpb  = (const float*)d_in[9];
    const float* lpg  = (const float*)d_in[10];
    const float* lpbt = (const float*)d_in[11];
    const float* blW  = (const float*)d_in[12];
    const float* blb  = (const float*)d_in[13];
    const float* blg  = (const float*)d_in[14];
    const float* blbt = (const float*)d_in[15];
    const float* llW  = (const float*)d_in[16];
    const float* llb  = (const float*)d_in[17];
    const float* llg  = (const float*)d_in[18];
    const float* llbt = (const float*)d_in[19];
    const int* srcp = (const int*)d_in[20];
    const int* dstp = (const int*)d_in[21];
    const int* gidp = (const int*)d_in[22];
    float* out = (float*)d_out;

    int N = in_sizes[0] / 64;
    int E = in_sizes[20];
    int nb = (N + 1023) / 1024;

    // workspace layout
    float* wsf = (float*)d_ws;
    _Float16* fsh = (_Float16*)wsf;                  // N*256 f16 = N*128 float slots
    _Float16* fdh = (_Float16*)(wsf + (size_t)N * 128);   // N*256 f16
    float* hmean = wsf + (size_t)N * 256;            // N*64
    float* pbuf  = hmean + (size_t)N * 64;           // 3*8192
    float* bnA   = pbuf + 3 * 8192;                  // 4*64
    float* bnB   = bnA + 256;                        // 4*64
    float* q     = bnB + 256;                        // 8192
    float* hh    = q + 8192;                         // 8192
    float* zstart = hh + 8192;
    float* bnsum = zstart;                           // 3*64
    float* bnsq  = bnsum + 192;                      // 3*64
    float* qsum  = bnsq + 192;                       // 3*64
    float* qsq   = qsum + 192;                       // 3*64
    float* hsum  = qsq + 192;                        // 64
    float* hsq   = hsum + 64;                        // 64
    float* S     = hsq + 64;                         // 3*8192
    int* deg     = (int*)(S + 3 * 8192);             // N
    int* cursor  = deg + N;                          // N
    int* zend    = cursor + N;
    int* cntg    = zend;                             // 128
    int* gstart  = cntg + 128;                       // 128
    int* row_ptr = gstart + 128;                     // N+1
    int* col_src = row_ptr + (N + 1);                // E
    int* bsum    = col_src + E;                      // nb (<=64)
    int* boff    = bsum + 64;                        // nb (<=64)

    size_t zbytes = (size_t)((char*)zend - (char*)zstart);
    hipMemsetAsync(zstart, 0, zbytes, stream);
    hipLaunchKernelGGL(init_affine_kernel, dim3(1), dim3(64), 0, stream, bnA, bnB);
    hipLaunchKernelGGL(hist_kernel, dim3((E + 255) / 256), dim3(256), 0, stream, dstp, deg, E);
    hipLaunchKernelGGL(bounds_kernel, dim3((N + 255) / 256), dim3(256), 0, stream, gidp, gstart, N);
    hipLaunchKernelGGL(cnt_diff_kernel, dim3(1), dim3(128), 0, stream, gstart, cntg, N);
    hipLaunchKernelGGL(scan_sums_kernel, dim3(nb), dim3(256), 0, stream, deg, bsum, N);
    hipLaunchKernelGGL(scan_offsets_kernel, dim3(1), dim3(64), 0, stream, bsum, boff, row_ptr + N, nb);
    hipLaunchKernelGGL(scan_final_kernel, dim3(nb), dim3(256), 0, stream, deg, boff, row_ptr, N);
    hipLaunchKernelGGL(scatter_kernel, dim3((E + 255) / 256), dim3(256), 0, stream,
                       srcp, dstp, row_ptr, cursor, col_src, E);

    for (int l = 0; l < 3; l++) {
        const float* hsrcp = (l == 0) ? feat : hmean;
        hipLaunchKernelGGL(gemm_kernel, dim3((N + 63) / 64, 2), dim3(256), 0, stream,
                           hsrcp, bnA + l * 64, bnB + l * 64,
                           Wsrc + (size_t)l * 64 * 256, bsrc + l * 256,
                           Wdst + (size_t)l * 64 * 256, bdst + l * 256, fsh, fdh, N);
        hipLaunchKernelGGL(gat_kernel, dim3((N + 3) / 4), dim3(256), 0, stream,
                           fsh, fdh, attn + l * 256, row_ptr, col_src, hmean, N);
        hipLaunchKernelGGL(stats_kernel, dim3(128), dim3(256), 0, stream,
                           hmean, gidp, bnsum + l * 64, bnsq + l * 64, S + l * 8192, N);
        hipLaunchKernelGGL(pooled_a_kernel, dim3(128), dim3(256), 0, stream,
                           bnsum + l * 64, bnsq + l * 64, S + l * 8192, cntg,
                           bn_g + l * 64, bn_b + l * 64,
                           lpW + (size_t)l * 64 * 64, lpb + l * 64,
                           q, qsum + l * 64, qsq + l * 64, N);
        hipLaunchKernelGGL(pooled_b_kernel, dim3(1), dim3(256), 0, stream,
                           bnsum + l * 64, bnsq + l * 64, q, qsum + l * 64, qsq + l * 64,
                           bn_g + l * 64, bn_b + l * 64, lpg + l * 64, lpbt + l * 64,
                           bnA + (l + 1) * 64, bnB + (l + 1) * 64, pbuf + l * 8192, N);
    }
    hipLaunchKernelGGL(head_gemm_kernel, dim3(128), dim3(256), 0, stream,
                       pbuf, blW, blb, hh, hsum, hsq);
    hipLaunchKernelGGL(head_finish_kernel, dim3(1), dim3(256), 0, stream,
                       hh, hsum, hsq, blg, blbt, llW, llb, llg, llbt, out);
}

// Round 5
// 600.572 us; speedup vs baseline: 2.2497x; 1.0141x over previous
//
#include <hip/hip_runtime.h>
#include <cmath>

#define NH 4
#define NG 128

typedef _Float16 half8 __attribute__((ext_vector_type(8)));
typedef _Float16 half4v __attribute__((ext_vector_type(4)));
typedef _Float16 half2v __attribute__((ext_vector_type(2)));
typedef float f32x4 __attribute__((ext_vector_type(4)));

#if defined(__has_builtin)
# if __has_builtin(__builtin_amdgcn_fdot2)
#  define USE_FDOT2 1
# endif
# if __has_builtin(__builtin_amdgcn_update_dpp)
#  define USE_DPP 1
# endif
#endif

// sum over each aligned 8-lane group, all lanes get result (DPP, no LDS)
__device__ inline float dpp_sum8(float p) {
#ifdef USE_DPP
    int pi = __builtin_bit_cast(int, p);
    int a = __builtin_amdgcn_update_dpp(0, pi, 0xB1, 0xF, 0xF, true);   // quad_perm [1,0,3,2]
    p += __builtin_bit_cast(float, a);
    pi = __builtin_bit_cast(int, p);
    a = __builtin_amdgcn_update_dpp(0, pi, 0x4E, 0xF, 0xF, true);       // quad_perm [2,3,0,1]
    p += __builtin_bit_cast(float, a);
    pi = __builtin_bit_cast(int, p);
    a = __builtin_amdgcn_update_dpp(0, pi, 0x141, 0xF, 0xF, true);      // row_half_mirror
    p += __builtin_bit_cast(float, a);
    return p;
#else
    p += __shfl_xor(p, 1); p += __shfl_xor(p, 2); p += __shfl_xor(p, 4);
    return p;
#endif
}

// ---------------- init / CSR build ----------------

__global__ void __launch_bounds__(256) hist_kernel(const int* __restrict__ dst,
                                                   int* __restrict__ deg, int E) {
    int e = blockIdx.x * 256 + threadIdx.x;
    if (e < E) atomicAdd(&deg[dst[e]], 1);
}

// graph_ids sorted -> boundary positions, no atomics
__global__ void __launch_bounds__(256) bounds_kernel(const int* __restrict__ gid,
                                                     int* __restrict__ start, int N) {
    int n = blockIdx.x * 256 + threadIdx.x;
    if (n >= N) return;
    int a = gid[n];
    if (n == 0)
        for (int g = 0; g <= a; g++) start[g] = 0;
    int b = (n + 1 < N) ? gid[n + 1] : NG;
    for (int g = a + 1; g <= b && g < NG; g++) start[g] = n + 1;
}

__global__ void __launch_bounds__(128) cnt_diff_kernel(const int* __restrict__ start,
                                                       int* __restrict__ cntg, int N) {
    int g = threadIdx.x;
    int s1 = (g == NG - 1) ? N : start[g + 1];
    cntg[g] = s1 - start[g];
}

// 3-phase exclusive scan of deg[N] -> row_ptr[N+1]
__global__ void __launch_bounds__(256) scan_sums_kernel(const int* __restrict__ deg,
                                                        int* __restrict__ bsum, int N) {
    __shared__ int red[256];
    int t = threadIdx.x;
    int base = blockIdx.x * 1024 + t * 4;
    int s = 0;
#pragma unroll
    for (int j = 0; j < 4; j++) { int i = base + j; if (i < N) s += deg[i]; }
    red[t] = s;
    __syncthreads();
    for (int off = 128; off > 0; off >>= 1) {
        if (t < off) red[t] += red[t + off];
        __syncthreads();
    }
    if (t == 0) bsum[blockIdx.x] = red[0];
}

__global__ void scan_offsets_kernel(const int* __restrict__ bsum, int* __restrict__ boff,
                                    int* __restrict__ row_ptr_N, int nb) {
    if (threadIdx.x == 0) {
        int acc = 0;
        for (int b = 0; b < nb; b++) { boff[b] = acc; acc += bsum[b]; }
        row_ptr_N[0] = acc;
    }
}

__global__ void __launch_bounds__(256) scan_final_kernel(const int* __restrict__ deg,
                                                         const int* __restrict__ boff,
                                                         int* __restrict__ row_ptr, int N) {
    __shared__ int red[256];
    int t = threadIdx.x;
    int base = blockIdx.x * 1024 + t * 4;
    int d[4];
    int s = 0;
#pragma unroll
    for (int j = 0; j < 4; j++) {
        int i = base + j;
        d[j] = (i < N) ? deg[i] : 0;
        s += d[j];
    }
    red[t] = s;
    __syncthreads();
    for (int off = 1; off < 256; off <<= 1) {
        int v = (t >= off) ? red[t - off] : 0;
        __syncthreads();
        red[t] += v;
        __syncthreads();
    }
    int excl = red[t] - s + boff[blockIdx.x];
#pragma unroll
    for (int j = 0; j < 4; j++) {
        int i = base + j;
        if (i < N) row_ptr[i] = excl;
        excl += d[j];
    }
}

__global__ void __launch_bounds__(256) scatter_kernel(const int* __restrict__ src,
                                                      const int* __restrict__ dst,
                                                      const int* __restrict__ row_ptr,
                                                      int* __restrict__ cursor,
                                                      int* __restrict__ col_src, int E) {
    int e = blockIdx.x * 256 + threadIdx.x;
    if (e < E) {
        int d = dst[e];
        int pos = row_ptr[d] + atomicAdd(&cursor[d], 1);
        col_src[pos] = src[e];
    }
}

// ---------------- one-time: W [l][m][k][c] f32 -> Wt [l*2+m][c][k] f16; init bnA/bnB ------

__global__ void __launch_bounds__(256) wcvt_kernel(
    const float* __restrict__ Wsrc, const float* __restrict__ Wdst,
    _Float16* __restrict__ Wt, float* bnA, float* bnB)
{
    __shared__ _Float16 lt[256 * 66];
    int b = blockIdx.x;                         // b = l*2 + m
    const float* W = (b & 1) ? (Wdst + (size_t)(b >> 1) * 16384)
                             : (Wsrc + (size_t)(b >> 1) * 16384);
    _Float16* o = Wt + (size_t)b * 16384;
    int t = threadIdx.x;
    for (int i = t; i < 16384; i += 256) {
        int k = i >> 8, c = i & 255;
        lt[c * 66 + k] = (_Float16)W[i];
    }
    __syncthreads();
    for (int i = t; i < 16384; i += 256) {
        int c = i >> 6, k = i & 63;
        o[i] = lt[c * 66 + k];
    }
    if (b == 0 && t < 64) { bnA[t] = 1.f; bnB[t] = 0.f; }
}

// ---------------- fused BN-affine + dual GEMM via f16 MFMA, direct-global B frags --------
// grid (ceil(N/64), 2): y=0 -> fs, y=1 -> fd. Block 256 = 4 waves; wave w owns 64 cols.

__global__ void __launch_bounds__(256) gemm_kernel(
    const float* __restrict__ h, const float* __restrict__ bnA, const float* __restrict__ bnB,
    const _Float16* __restrict__ Wt,            // [2][256][64] f16 for this layer
    const float* __restrict__ bsrc, const float* __restrict__ bdst,
    _Float16* __restrict__ fsh, _Float16* __restrict__ fdh, int N)
{
    __shared__ _Float16 As[64 * 72];            // row stride 144 B (16B-aligned frags)
    int t = threadIdx.x;
    int row0 = blockIdx.x * 64;
    const _Float16* Wm = Wt + (size_t)blockIdx.y * 16384;
    const float* bias  = blockIdx.y ? bdst : bsrc;
    _Float16* out      = blockIdx.y ? fdh : fsh;

    // stage A: thread handles (row r, k-group kg of 4) -> float4 load, half4 LDS store
#pragma unroll
    for (int i = 0; i < 4; i++) {
        int flat = i * 256 + t;
        int r = flat >> 4, kg = flat & 15;
        int gr = row0 + r;
        float4 hv = make_float4(0.f, 0.f, 0.f, 0.f);
        if (gr < N) hv = *(const float4*)(h + (size_t)gr * 64 + kg * 4);
        float4 a4 = *(const float4*)(bnA + kg * 4);
        float4 b4 = *(const float4*)(bnB + kg * 4);
        half4v o4;
        o4[0] = (_Float16)(hv.x * a4.x + b4.x);
        o4[1] = (_Float16)(hv.y * a4.y + b4.y);
        o4[2] = (_Float16)(hv.z * a4.z + b4.z);
        o4[3] = (_Float16)(hv.w * a4.w + b4.w);
        *(half4v*)(&As[r * 72 + kg * 4]) = o4;
    }
    __syncthreads();

    int w = t >> 6, lane = t & 63;
    int n16 = lane & 15, q = lane >> 4;
    int cw = w * 64;
    f32x4 acc[4][4];
#pragma unroll
    for (int mt = 0; mt < 4; mt++)
#pragma unroll
        for (int nt = 0; nt < 4; nt++) acc[mt][nt] = (f32x4)(0.f);
    float bv[4];
#pragma unroll
    for (int nt = 0; nt < 4; nt++) bv[nt] = bias[cw + nt * 16 + n16];

#pragma unroll
    for (int kk = 0; kk < 2; kk++) {
        half8 af[4], bf[4];
#pragma unroll
        for (int mt = 0; mt < 4; mt++)
            af[mt] = *(const half8*)(&As[(mt * 16 + n16) * 72 + kk * 32 + q * 8]);
#pragma unroll
        for (int nt = 0; nt < 4; nt++)
            bf[nt] = *(const half8*)(Wm + (size_t)(cw + nt * 16 + n16) * 64 + kk * 32 + q * 8);
#pragma unroll
        for (int mt = 0; mt < 4; mt++)
#pragma unroll
            for (int nt = 0; nt < 4; nt++)
                acc[mt][nt] = __builtin_amdgcn_mfma_f32_16x16x32_f16(af[mt], bf[nt], acc[mt][nt], 0, 0, 0);
    }
    // epilogue: C/D layout col=lane&15, row=q*4+reg
#pragma unroll
    for (int mt = 0; mt < 4; mt++) {
#pragma unroll
        for (int i = 0; i < 4; i++) {
            int gr = row0 + mt * 16 + q * 4 + i;
            if (gr < N) {
#pragma unroll
                for (int nt = 0; nt < 4; nt++)
                    out[(size_t)gr * 256 + cw + nt * 16 + n16] = (_Float16)(acc[mt][nt][i] + bv[nt]);
            }
        }
    }
}

// ---------------- fused GATv2 edge phase: wave/node, DPP logit-reduce, SW pipeline -------
// lane = e2*32 + d8: e2 = edge slot, d8 = 8-dim group (16 B/lane). 4 edges per iteration.

__global__ void __launch_bounds__(256) gat_kernel(
    const _Float16* __restrict__ fsh, const _Float16* __restrict__ fdh,
    const float* __restrict__ attn,
    const int* __restrict__ row_ptr, const int* __restrict__ col_src,
    float* __restrict__ hmean, int N)
{
    int wid = (blockIdx.x << 2) + (threadIdx.x >> 6);
    if (wid >= N) return;
    int lane = threadIdx.x & 63;
    int e2 = lane >> 5;
    int d8 = lane & 31;
    int rs = row_ptr[wid];
    int deg = row_ptr[wid + 1] - rs;

    half8 fdv = *(const half8*)(fdh + (size_t)wid * 256 + d8 * 8);
    const float* ap = attn + (d8 >> 3) * 64 + (d8 & 7) * 8;
    half8 att;
#pragma unroll
    for (int j = 0; j < 8; j++) att[j] = (_Float16)ap[j];
    half8 k02;
#pragma unroll
    for (int j = 0; j < 8; j++) k02[j] = (_Float16)0.2f;

    float acc[8];
#pragma unroll
    for (int j = 0; j < 8; j++) acc[j] = 0.f;
    float l = 0.f;

    int s_reg = 0;
    if (lane < deg) s_reg = col_src[rs + lane];

    auto fetch = [&](int i, half8& a, half8& b, bool& va, bool& vb) {
        int idx0 = i + e2, idx1 = i + 2 + e2;
        va = idx0 < deg;
        vb = idx1 < deg;
        int c0 = va ? idx0 : 0;
        int c1 = vb ? idx1 : 0;
        int s0 = (c0 < 64) ? __shfl(s_reg, c0, 64) : col_src[rs + c0];
        int s1 = (c1 < 64) ? __shfl(s_reg, c1, 64) : col_src[rs + c1];
        a = *(const half8*)(fsh + (size_t)s0 * 256 + d8 * 8);
        b = *(const half8*)(fsh + (size_t)s1 * 256 + d8 * 8);
    };

    half8 ca, cb;
    bool va = false, vb = false;
    if (deg > 0) fetch(0, ca, cb, va, vb);

    for (int i = 0; i < deg; i += 4) {
        half8 na, nb;
        bool nva = false, nvb = false;
        if (i + 4 < deg) fetch(i + 4, na, nb, nva, nvb);
#pragma unroll
        for (int u = 0; u < 2; u++) {
            half8 fv = u ? cb : ca;
            bool valid = u ? vb : va;
            half8 x = fv + fdv;
            half8 lx = __builtin_elementwise_max(x, x * k02);
            float p = 0.f;
#ifdef USE_FDOT2
#pragma unroll
            for (int j = 0; j < 4; j++) {
                half2v a2 = { lx[2 * j], lx[2 * j + 1] };
                half2v b2 = { att[2 * j], att[2 * j + 1] };
                p = __builtin_amdgcn_fdot2(a2, b2, p, false);
            }
#else
#pragma unroll
            for (int j = 0; j < 8; j++) p = fmaf((float)lx[j], (float)att[j], p);
#endif
            p = dpp_sum8(p);
            float e = valid ? __expf(p) : 0.f;
            l += e;
#pragma unroll
            for (int j = 0; j < 8; j++) acc[j] = fmaf(e, (float)fv[j], acc[j]);
        }
        ca = na; cb = nb; va = nva; vb = nvb;
    }
    // combine the two edge-slot halves
    l += __shfl_xor(l, 32);
#pragma unroll
    for (int j = 0; j < 8; j++) acc[j] += __shfl_xor(acc[j], 32);

    float inv = (l > 0.f) ? 0.25f / l : 0.f;   // fold head-mean (relu(c*x)=c*relu(x), c>0)
    float m[8];
#pragma unroll
    for (int j = 0; j < 8; j++) m[j] = fmaxf(acc[j] * inv, 0.f);
    // cross-head sum: lanes d8, d8^8, d8^16
#pragma unroll
    for (int j = 0; j < 8; j++) {
        m[j] += __shfl_xor(m[j], 8);
        m[j] += __shfl_xor(m[j], 16);
    }
    if (lane < 8) {
        float4 o0 = make_float4(m[0], m[1], m[2], m[3]);
        float4 o1 = make_float4(m[4], m[5], m[6], m[7]);
        *(float4*)(hmean + (size_t)wid * 64 + d8 * 8) = o0;
        *(float4*)(hmean + (size_t)wid * 64 + d8 * 8 + 4) = o1;
    }
}

// ---------------- BN stats + graph segment sums (raw hmean) ----------------

__global__ void __launch_bounds__(256) stats_kernel(
    const float* __restrict__ hmean, const int* __restrict__ gid,
    float* __restrict__ bnsum, float* __restrict__ bnsumsq,
    float* __restrict__ S, int N)
{
    __shared__ float bs[4][64], bq[4][64];
    int t = threadIdx.x, lane = t & 63, w = t >> 6;
    int wglobal = blockIdx.x * 4 + w;
    int chunk = (N + 511) >> 9;
    int n0 = wglobal * chunk;
    int n1 = min(n0 + chunk, N);
    float sum = 0.f, sq = 0.f, run = 0.f;
    int cur = -1;
    for (int n = n0; n < n1; n++) {
        float v = hmean[(size_t)n * 64 + lane];
        int g = gid[n];
        if (g != cur) {
            if (cur >= 0) atomicAdd(&S[cur * 64 + lane], run);
            run = 0.f;
            cur = g;
        }
        run += v;
        sum += v;
        sq = fmaf(v, v, sq);
    }
    if (cur >= 0) atomicAdd(&S[cur * 64 + lane], run);
    bs[w][lane] = sum;
    bq[w][lane] = sq;
    __syncthreads();
    if (w == 0) {
        float s2 = bs[0][lane] + bs[1][lane] + bs[2][lane] + bs[3][lane];
        float q2 = bq[0][lane] + bq[1][lane] + bq[2][lane] + bq[3][lane];
        atomicAdd(&bnsum[lane], s2);
        atomicAdd(&bnsumsq[lane], q2);
    }
}

// ---------------- pooled path A: per-graph MLP row (128 blocks) ----------------

__global__ void __launch_bounds__(256) pooled_a_kernel(
    const float* __restrict__ bnsum, const float* __restrict__ bnsumsq,
    const float* __restrict__ S, const int* __restrict__ cntg,
    const float* __restrict__ bn_g, const float* __restrict__ bn_b,
    const float* __restrict__ lpW, const float* __restrict__ lpb,
    float* __restrict__ q, float* __restrict__ qsum, float* __restrict__ qsq, int N)
{
    __shared__ float sv[64];
    __shared__ float partial[4][64];
    int g = blockIdx.x;
    int t = threadIdx.x;
    if (t < 64) {
        float mu = bnsum[t] / (float)N;
        float var = bnsumsq[t] / (float)N - mu * mu;
        float a = bn_g[t] / sqrtf(var + 1e-5f);
        float b = bn_b[t] - mu * a;
        sv[t] = a * S[g * 64 + t] + b * (float)cntg[g];
    }
    __syncthreads();
    int f = t & 63, kc = t >> 6;
    float acc = 0.f;
#pragma unroll
    for (int k = kc * 16; k < kc * 16 + 16; k++)
        acc = fmaf(sv[k], lpW[k * 64 + f], acc);
    partial[kc][f] = acc;
    __syncthreads();
    if (t < 64) {
        float v = partial[0][t] + partial[1][t] + partial[2][t] + partial[3][t] + lpb[t];
        v = fmaxf(v, 0.f);
        q[g * 64 + t] = v;
        atomicAdd(&qsum[t], v);
        atomicAdd(&qsq[t], v * v);
    }
}

// ---------------- pooled path B: BN over graphs + next-layer node-BN affine ----------------

__global__ void __launch_bounds__(256) pooled_b_kernel(
    const float* __restrict__ bnsum, const float* __restrict__ bnsumsq,
    const float* __restrict__ q, const float* __restrict__ qsum, const float* __restrict__ qsq,
    const float* __restrict__ bn_g, const float* __restrict__ bn_b,
    const float* __restrict__ lpg, const float* __restrict__ lpbt,
    float* __restrict__ bnA_out, float* __restrict__ bnB_out,
    float* __restrict__ p_out, int N)
{
    __shared__ float mu2[64], sc2[64];
    int t = threadIdx.x;
    if (t < 64) {
        float mu = bnsum[t] / (float)N;
        float var = bnsumsq[t] / (float)N - mu * mu;
        float a = bn_g[t] / sqrtf(var + 1e-5f);
        bnA_out[t] = a;
        bnB_out[t] = bn_b[t] - mu * a;
        float m = qsum[t] * (1.f / 128.f);
        float v = qsq[t] * (1.f / 128.f) - m * m;
        mu2[t] = m;
        sc2[t] = lpg[t] / sqrtf(v + 1e-5f);
    }
    __syncthreads();
    for (int i = t; i < 128 * 64; i += 256) {
        int ff = i & 63;
        p_out[i] = (q[i] - mu2[ff]) * sc2[ff] + lpbt[ff];
    }
}

// ---------------- head A: hh = relu(cat @ blW + blb), 128 blocks, stats atomics ----------------

__global__ void __launch_bounds__(256) head_gemm_kernel(
    const float* __restrict__ p, const float* __restrict__ blW, const float* __restrict__ blb,
    float* __restrict__ hh, float* __restrict__ hsum, float* __restrict__ hsq)
{
    __shared__ float cat[192];
    __shared__ float partial[4][64];
    int g = blockIdx.x;
    int t = threadIdx.x;
    if (t < 192) cat[t] = p[(t >> 6) * 8192 + g * 64 + (t & 63)];
    __syncthreads();
    int f = t & 63, kc = t >> 6;
    float acc = 0.f;
#pragma unroll
    for (int k = kc * 48; k < kc * 48 + 48; k++)
        acc = fmaf(cat[k], blW[k * 64 + f], acc);
    partial[kc][f] = acc;
    __syncthreads();
    if (t < 64) {
        float v = partial[0][t] + partial[1][t] + partial[2][t] + partial[3][t] + blb[t];
        v = fmaxf(v, 0.f);
        hh[g * 64 + t] = v;
        atomicAdd(&hsum[t], v);
        atomicAdd(&hsq[t], v * v);
    }
}

// ---------------- head B: BN, second linear, BN, log_softmax ----------------

__global__ void __launch_bounds__(256) head_finish_kernel(
    const float* __restrict__ hh, const float* __restrict__ hsum, const float* __restrict__ hsq,
    const float* __restrict__ blg, const float* __restrict__ blbt,
    const float* __restrict__ llW, const float* __restrict__ llb,
    const float* __restrict__ llg, const float* __restrict__ llbt,
    float* __restrict__ out)
{
    __shared__ float hn[128][65];
    __shared__ float ph[128][12];
    __shared__ float mu[64], sc[64];
    __shared__ float mj[12], scj[12];
    __shared__ float sW[640];
    int t = threadIdx.x;
    if (t < 64) {
        float m = hsum[t] * (1.f / 128.f);
        float v = hsq[t] * (1.f / 128.f) - m * m;
        mu[t] = m;
        sc[t] = blg[t] / sqrtf(v + 1e-5f);
    }
    for (int i = t; i < 640; i += 256) sW[i] = llW[i];
    __syncthreads();
    for (int i = t; i < 8192; i += 256) {
        int g = i >> 6, ff = i & 63;
        float v = (hh[i] - mu[ff]) * sc[ff] + blbt[ff];
        out[1280 + i] = v;          // output 1: pooled_hh
        hn[g][ff] = v;
    }
    __syncthreads();
    for (int i = t; i < 1280; i += 256) {
        int g = i / 10, j = i - g * 10;
        float s = llb[j];
#pragma unroll 8
        for (int k = 0; k < 64; k++) s = fmaf(hn[g][k], sW[k * 10 + j], s);
        ph[g][j] = fmaxf(s, 0.f);
    }
    __syncthreads();
    if (t < 10) {
        float m = 0.f;
        for (int g = 0; g < 128; g++) m += ph[g][t];
        m *= (1.f / 128.f);
        float v = 0.f;
        for (int g = 0; g < 128; g++) { float d = ph[g][t] - m; v = fmaf(d, d, v); }
        v *= (1.f / 128.f);
        mj[t] = m;
        scj[t] = llg[t] / sqrtf(v + 1e-5f);
    }
    __syncthreads();
    if (t < 128) {
        float vals[10];
        float mx = -1e30f;
        for (int j = 0; j < 10; j++) {
            vals[j] = (ph[t][j] - mj[j]) * scj[j] + llbt[j];
            mx = fmaxf(mx, vals[j]);
        }
        float se = 0.f;
        for (int j = 0; j < 10; j++) se += __expf(vals[j] - mx);
        float lse = logf(se) + mx;
        for (int j = 0; j < 10; j++) out[t * 10 + j] = vals[j] - lse;   // output 0
    }
}

// ---------------- launcher ----------------

extern "C" void kernel_launch(void* const* d_in, const int* in_sizes, int n_in,
                              void* d_out, int out_size, void* d_ws, size_t ws_size,
                              hipStream_t stream)
{
    const float* feat = (const float*)d_in[0];
    const float* Wsrc = (const float*)d_in[1];
    const float* bsrc = (const float*)d_in[2];
    const float* Wdst = (const float*)d_in[3];
    const float* bdst = (const float*)d_in[4];
    const float* attn = (const float*)d_in[5];
    const float* bn_g = (const float*)d_in[6];
    const float* bn_b = (const float*)d_in[7];
    const float* lpW  = (const float*)d_in[8];
    const float* lpb  = (const float*)d_in[9];
    const float* lpg  = (const float*)d_in[10];
    const float* lpbt = (const float*)d_in[11];
    const float* blW  = (const float*)d_in[12];
    const float* blb  = (const float*)d_in[13];
    const float* blg  = (const float*)d_in[14];
    const float* blbt = (const float*)d_in[15];
    const float* llW  = (const float*)d_in[16];
    const float* llb  = (const float*)d_in[17];
    const float* llg  = (const float*)d_in[18];
    const float* llbt = (const float*)d_in[19];
    const int* srcp = (const int*)d_in[20];
    const int* dstp = (const int*)d_in[21];
    const int* gidp = (const int*)d_in[22];
    float* out = (float*)d_out;

    int N = in_sizes[0] / 64;
    int E = in_sizes[20];
    int nb = (N + 1023) / 1024;

    // workspace layout
    float* wsf = (float*)d_ws;
    _Float16* fsh = (_Float16*)wsf;                       // N*256 f16
    _Float16* fdh = (_Float16*)(wsf + (size_t)N * 128);   // N*256 f16
    float* hmean = wsf + (size_t)N * 256;            // N*64
    float* pbuf  = hmean + (size_t)N * 64;           // 3*8192
    float* bnA   = pbuf + 3 * 8192;                  // 4*64
    float* bnB   = bnA + 256;                        // 4*64
    float* q     = bnB + 256;                        // 8192
    float* hh    = q + 8192;                         // 8192
    _Float16* Wt16 = (_Float16*)(hh + 8192);         // 6*16384 f16 = 49152 float slots
    float* zstart = hh + 8192 + 49152;
    float* bnsum = zstart;                           // 3*64
    float* bnsq  = bnsum + 192;                      // 3*64
    float* qsum  = bnsq + 192;                       // 3*64
    float* qsq   = qsum + 192;                       // 3*64
    float* hsum  = qsq + 192;                        // 64
    float* hsq   = hsum + 64;                        // 64
    float* S     = hsq + 64;                         // 3*8192
    int* deg     = (int*)(S + 3 * 8192);             // N
    int* cursor  = deg + N;                          // N
    int* zend    = cursor + N;
    int* cntg    = zend;                             // 128
    int* gstart  = cntg + 128;                       // 128
    int* row_ptr = gstart + 128;                     // N+1
    int* col_src = row_ptr + (N + 1);                // E
    int* bsum    = col_src + E;                      // nb (<=64)
    int* boff    = bsum + 64;                        // nb (<=64)

    size_t zbytes = (size_t)((char*)zend - (char*)zstart);
    hipMemsetAsync(zstart, 0, zbytes, stream);
    hipLaunchKernelGGL(wcvt_kernel, dim3(6), dim3(256), 0, stream, Wsrc, Wdst, Wt16, bnA, bnB);
    hipLaunchKernelGGL(hist_kernel, dim3((E + 255) / 256), dim3(256), 0, stream, dstp, deg, E);
    hipLaunchKernelGGL(bounds_kernel, dim3((N + 255) / 256), dim3(256), 0, stream, gidp, gstart, N);
    hipLaunchKernelGGL(cnt_diff_kernel, dim3(1), dim3(128), 0, stream, gstart, cntg, N);
    hipLaunchKernelGGL(scan_sums_kernel, dim3(nb), dim3(256), 0, stream, deg, bsum, N);
    hipLaunchKernelGGL(scan_offsets_kernel, dim3(1), dim3(64), 0, stream, bsum, boff, row_ptr + N, nb);
    hipLaunchKernelGGL(scan_final_kernel, dim3(nb), dim3(256), 0, stream, deg, boff, row_ptr, N);
    hipLaunchKernelGGL(scatter_kernel, dim3((E + 255) / 256), dim3(256), 0, stream,
                       srcp, dstp, row_ptr, cursor, col_src, E);

    for (int l = 0; l < 3; l++) {
        const float* hsrcp = (l == 0) ? feat : hmean;
        hipLaunchKernelGGL(gemm_kernel, dim3((N + 63) / 64, 2), dim3(256), 0, stream,
                           hsrcp, bnA + l * 64, bnB + l * 64,
                           Wt16 + (size_t)l * 32768, bsrc + l * 256, bdst + l * 256,
                           fsh, fdh, N);
        hipLaunchKernelGGL(gat_kernel, dim3((N + 3) / 4), dim3(256), 0, stream,
                           fsh, fdh, attn + l * 256, row_ptr, col_src, hmean, N);
        hipLaunchKernelGGL(stats_kernel, dim3(128), dim3(256), 0, stream,
                           hmean, gidp, bnsum + l * 64, bnsq + l * 64, S + l * 8192, N);
        hipLaunchKernelGGL(pooled_a_kernel, dim3(128), dim3(256), 0, stream,
                           bnsum + l * 64, bnsq + l * 64, S + l * 8192, cntg,
                           bn_g + l * 64, bn_b + l * 64,
                           lpW + (size_t)l * 64 * 64, lpb + l * 64,
                           q, qsum + l * 64, qsq + l * 64, N);
        hipLaunchKernelGGL(pooled_b_kernel, dim3(1), dim3(256), 0, stream,
                           bnsum + l * 64, bnsq + l * 64, q, qsum + l * 64, qsq + l * 64,
                           bn_g + l * 64, bn_b + l * 64, lpg + l * 64, lpbt + l * 64,
                           bnA + (l + 1) * 64, bnB + (l + 1) * 64, pbuf + l * 8192, N);
    }
    hipLaunchKernelGGL(head_gemm_kernel, dim3(128), dim3(256), 0, stream,
                       pbuf, blW, blb, hh, hsum, hsq);
    hipLaunchKernelGGL(head_finish_kernel, dim3(1), dim3(256), 0, stream,
                       hh, hsum, hsq, blg, blbt, llW, llb, llg, llbt, out);
}